// Round 8
// baseline (153.789 us; speedup 1.0000x reference)
//
#include <hip/hip_runtime.h>
#include <math.h>

#define NN 4096
#define HH 8
constexpr float SCALE = 0.17677669529663687f;   // 1/sqrt(32)
constexpr float LOG2E = 1.4426950408889634f;
constexpr float SC2   = SCALE * LOG2E;          // folded into Q columns of Wqkv

typedef __bf16 bf16;
typedef __bf16 bf16x8 __attribute__((ext_vector_type(8)));
typedef __bf16 bf16x4 __attribute__((ext_vector_type(4)));
typedef float  f32x4  __attribute__((ext_vector_type(4)));

#define MFMA(a, b, c) __builtin_amdgcn_mfma_f32_16x16x32_bf16((a), (b), (c), 0, 0, 0)

// ---------------------------------------------------------------------------
// W [K][N] fp32 -> W^T hi/lo bf16 [N][K]; optionally scale cols n<256 by SC2.
// ---------------------------------------------------------------------------
template <int K, int N, bool SCALEQ>
__device__ __forceinline__ void wcast_body(const float* __restrict__ W,
                                           bf16* __restrict__ WhT,
                                           bf16* __restrict__ WlT,
                                           int n0, int k0, int t,
                                           float (*tile)[65]) {
#pragma unroll
    for (int p = 0; p < 16; ++p) {
        const int r = p * 4 + (t >> 6);
        const int c = t & 63;
        tile[r][c] = W[(size_t)(k0 + r) * N + n0 + c];
    }
    __syncthreads();
    const int nr = t >> 2, kc0 = (t & 3) * 16;
    const float sc = (SCALEQ && (n0 + nr) < 256) ? SC2 : 1.0f;
    bf16x8 h[2], l[2];
#pragma unroll
    for (int g = 0; g < 2; ++g)
#pragma unroll
        for (int j = 0; j < 8; ++j) {
            const float v = tile[kc0 + g * 8 + j][nr] * sc;
            const bf16 hh = (bf16)v;
            h[g][j] = hh;
            l[g][j] = (bf16)(v - (float)hh);
        }
    const size_t ob = (size_t)(n0 + nr) * K + k0 + kc0;
    *(bf16x8*)&WhT[ob] = h[0];
    *(bf16x8*)&WhT[ob + 8] = h[1];
    *(bf16x8*)&WlT[ob] = l[0];
    *(bf16x8*)&WlT[ob + 8] = l[1];
}

// ---------------------------------------------------------------------------
// Fused preprocessing. Block ranges:
//  [0,1024)      xcast
//  [1024,1072)   wcast Wqkv (Q cols pre-scaled)
//  [1072,1088)   wcast Wout
//  [1088,1216)   pe_proj -> ppb = -(pe@Wpe+bpe)*log2e - 8  (additive bias)
//  [1216]        bqkv scale
//  [1217,2273)   zero aof (4 MB) + lvec (128 KB) for the attn atomics
// ---------------------------------------------------------------------------
__global__ __launch_bounds__(256) void preproc_kernel(
    const float* __restrict__ x, const float* __restrict__ Wqkv,
    const float* __restrict__ Wout, const float* __restrict__ bqkv,
    const float* __restrict__ pe, const float* __restrict__ Wpe,
    const float* __restrict__ bpe,
    bf16* __restrict__ xh, bf16* __restrict__ xl,
    bf16* __restrict__ WqkvhT, bf16* __restrict__ WqkvlT,
    bf16* __restrict__ WouthT, bf16* __restrict__ WoutlT,
    float* __restrict__ bqkv_s, float* __restrict__ ppb,
    uint4* __restrict__ zbase) {
    __shared__ float tile[64][65];
    const int b = blockIdx.x, t = threadIdx.x;
    if (b < 1024) {
        const int i = (b * 256 + t) * 4;
        const float4 v = *(const float4*)&x[i];
        bf16x4 h, l;
        const float vv[4] = {v.x, v.y, v.z, v.w};
#pragma unroll
        for (int r = 0; r < 4; ++r) {
            h[r] = (bf16)vv[r];
            l[r] = (bf16)(vv[r] - (float)h[r]);
        }
        *(bf16x4*)&xh[i] = h;
        *(bf16x4*)&xl[i] = l;
    } else if (b < 1072) {
        const int bb = b - 1024;
        wcast_body<256, 768, true>(Wqkv, WqkvhT, WqkvlT, (bb % 12) * 64, (bb / 12) * 64, t, tile);
    } else if (b < 1088) {
        const int bb = b - 1072;
        wcast_body<256, 256, false>(Wout, WouthT, WoutlT, (bb % 4) * 64, (bb / 4) * 64, t, tile);
    } else if (b < 1216) {
        const int idx = (b - 1088) * 256 + t;
        const int h = idx >> 12;
        const int n = idx & 4095;
        float acc = bpe[h];
#pragma unroll
        for (int k = 0; k < 16; ++k) acc += pe[n * 16 + k] * Wpe[k * 8 + h];
        ppb[h * NN + n] = -acc * LOG2E - 8.0f;
    } else if (b == 1216) {
        for (int i = t; i < 768; i += 256)
            bqkv_s[i] = bqkv[i] * (i < 256 ? SC2 : 1.0f);
    } else {
        zbase[(size_t)(b - 1217) * 256 + t] = uint4{0, 0, 0, 0};
    }
}

// ---------------------------------------------------------------------------
// Staged 3-term split-bf16 GEMM for QKV (round-6, proven).
// ---------------------------------------------------------------------------
template <int NOUT, int NTILE, typename OT>
__global__ __launch_bounds__(256, 2) void gemm3s_kernel(const bf16* __restrict__ Ah,
                                                        const bf16* __restrict__ Al,
                                                        const bf16* __restrict__ BhT,
                                                        const bf16* __restrict__ BlT,
                                                        const float* __restrict__ bias,
                                                        OT* __restrict__ C) {
    constexpr int NS = NTILE / 16;
    const int t = threadIdx.x, wave = t >> 6, lane = t & 63;
    const int quad = lane >> 4, i16 = lane & 15;
    const int m0 = blockIdx.x * 128 + wave * 32;
    const int n0 = blockIdx.y * NTILE;

    __shared__ __align__(16) bf16 Bs[NTILE * 512];

    {
        const int l = t & 63, i16l = l & 15, ql = l >> 4;
#pragma unroll
        for (int c = t >> 6; c < NS * 16; c += 4) {
            const bool lo = c >= NS * 8;
            const int cc = lo ? c - NS * 8 : c;
            const int nsi = cc >> 3, kc = cc & 7;
            const bf16* src = (lo ? BlT : BhT) +
                (size_t)(n0 + nsi * 16 + i16l) * 256 + kc * 32 + ql * 8;
            *(uint4*)&Bs[c * 512 + l * 8] = *(const uint4*)src;
        }
    }

    bf16x8 ah[2][8], al[2][8];
#pragma unroll
    for (int ms = 0; ms < 2; ++ms) {
        const size_t abase = (size_t)(m0 + ms * 16 + i16) * 256 + quad * 8;
#pragma unroll
        for (int kc = 0; kc < 8; ++kc) {
            ah[ms][kc] = *(const bf16x8*)&Ah[abase + kc * 32];
            al[ms][kc] = *(const bf16x8*)&Al[abase + kc * 32];
        }
    }
    __syncthreads();

#pragma unroll
    for (int nsi = 0; nsi < NS; ++nsi) {
        f32x4 acc[2];
        acc[0] = f32x4{0.f, 0.f, 0.f, 0.f};
        acc[1] = f32x4{0.f, 0.f, 0.f, 0.f};
#pragma unroll
        for (int kc = 0; kc < 8; ++kc) {
            const bf16x8 bh = *(const bf16x8*)&Bs[(nsi * 8 + kc) * 512 + lane * 8];
            const bf16x8 bl = *(const bf16x8*)&Bs[((NS + nsi) * 8 + kc) * 512 + lane * 8];
            acc[0] = MFMA(ah[0][kc], bh, acc[0]);
            acc[0] = MFMA(ah[0][kc], bl, acc[0]);
            acc[0] = MFMA(al[0][kc], bh, acc[0]);
            acc[1] = MFMA(ah[1][kc], bh, acc[1]);
            acc[1] = MFMA(ah[1][kc], bl, acc[1]);
            acc[1] = MFMA(al[1][kc], bh, acc[1]);
        }
        const int n = n0 + nsi * 16 + i16;
        const float b = bias[n];
#pragma unroll
        for (int ms = 0; ms < 2; ++ms)
#pragma unroll
            for (int r = 0; r < 4; ++r)
                C[(size_t)(m0 + ms * 16 + quad * 4 + r) * NOUT + n] = (OT)(acc[ms][r] + b);
    }
}

// ---------------------------------------------------------------------------
// K and V -> MFMA fragment order (plain bf16 cast; bias now rides the QK
// C-operand, so V is 2 d-tiles = 4 KB/tile).
// ---------------------------------------------------------------------------
__global__ __launch_bounds__(256) void kvtrans_kernel(const bf16* __restrict__ qkvb,
                                                      bf16* __restrict__ Kf,
                                                      bf16* __restrict__ Vf) {
    const int t = threadIdx.x;
    const int kt = blockIdx.y, h = blockIdx.x;
    __shared__ __align__(16) bf16 Ktile[64 * 32];
    __shared__ __align__(16) bf16 Vtile[64 * 32];
    {
        const int tok = kt * 64 + (t >> 2);
        const int d8 = (t & 3) * 8;
        *(uint4*)&Ktile[(t >> 2) * 32 + d8] =
            *(const uint4*)&qkvb[(size_t)tok * 768 + 256 + h * 32 + d8];
        *(uint4*)&Vtile[(t >> 2) * 32 + d8] =
            *(const uint4*)&qkvb[(size_t)tok * 768 + 512 + h * 32 + d8];
    }
    __syncthreads();
    const int ch = t >> 6, l = t & 63, quad = l >> 4, i16 = l & 15;
    {   // K frags: chunk ch = key-sub s
        bf16x8 o;
#pragma unroll
        for (int j = 0; j < 8; ++j) o[j] = Ktile[(ch * 16 + i16) * 32 + quad * 8 + j];
        *(bf16x8*)&Kf[((size_t)(h * 64 + kt) * 4 + ch) * 512 + l * 8] = o;
    }
    {   // V frags: chunk ch = dt*2+kc (A-operand layout for PV)
        const int dt = ch >> 1, kc = ch & 1;
        bf16x8 o;
#pragma unroll
        for (int j = 0; j < 8; ++j)
            o[j] = Vtile[(kc * 32 + quad * 8 + j) * 32 + dt * 16 + i16];
        *(bf16x8*)&Vf[((size_t)(h * 64 + kt) * 4 + ch) * 512 + l * 8] = o;
    }
}

// ---------------------------------------------------------------------------
// Fixed-m flash attention v4. grid (8 h, 64 qb, 2 key-half) = 1024 blocks
// (occupancy no longer grid-capped at 2 blocks/CU). Each wave: all 64
// queries, 8 key tiles. PE bias enters as the QK-MFMA C-operand; l is
// accumulated in-register from fp32 p. Partials merged in-block via LDS
// (aliased over Pt), then fp32 atomicAdd into aof/lvec (2 contributors per
// address -> deterministic).
// ---------------------------------------------------------------------------
__global__ __launch_bounds__(256, 3) void attn_kernel(const bf16* __restrict__ qkvb,
                                                      const bf16* __restrict__ Kf,
                                                      const bf16* __restrict__ Vf,
                                                      const float* __restrict__ ppb,
                                                      float* __restrict__ aof,
                                                      float* __restrict__ lvec) {
    const int t = threadIdx.x, w = t >> 6, lane = t & 63;
    const int quad = lane >> 4, i16 = lane & 15;
    const int qb = blockIdx.y, h = blockIdx.x, ksh = blockIdx.z;

    __shared__ __align__(16) bf16 Pt[4][4][16 * 72]; // 36.9 KB; epilogue aliases it

    const int q0 = qb * 64;
    bf16x8 qf[4];
#pragma unroll
    for (int qs = 0; qs < 4; ++qs)
        qf[qs] = *(const bf16x8*)&qkvb[(size_t)(q0 + qs * 16 + i16) * 768 + h * 32 + quad * 8];

    f32x4 o[2][4];
#pragma unroll
    for (int dt = 0; dt < 2; ++dt)
#pragma unroll
        for (int qs = 0; qs < 4; ++qs) o[dt][qs] = f32x4{0.f, 0.f, 0.f, 0.f};
    float lacc[4] = {0.f, 0.f, 0.f, 0.f};

    const bf16* kb = Kf + (size_t)(h * 64) * 2048 + lane * 8;
    const bf16* vb = Vf + (size_t)(h * 64) * 2048 + lane * 8;
    const float* pph = ppb + h * NN + quad * 4;

    const int kt0 = ksh * 32 + w * 8;
    for (int it = 0; it < 8; ++it) {
        const int kt = kt0 + it;
        bf16x8 kc4[4], vv[4];
        f32x4 bias[4];
#pragma unroll
        for (int s = 0; s < 4; ++s) {
            kc4[s] = *(const bf16x8*)&kb[((size_t)kt * 4 + s) * 512];
            vv[s]  = *(const bf16x8*)&vb[((size_t)kt * 4 + s) * 512];
            bias[s] = *(const f32x4*)&pph[kt * 64 + s * 16];
        }

        // QK^T with bias in C; P = exp2(.); l accumulates in fp32
#pragma unroll
        for (int qs = 0; qs < 4; ++qs) {
            f32x4 sf[4];
#pragma unroll
            for (int ks = 0; ks < 4; ++ks) sf[ks] = MFMA(kc4[ks], qf[qs], bias[ks]);
            float lq = 0.f;
#pragma unroll
            for (int ks = 0; ks < 4; ++ks) {
                float p[4];
#pragma unroll
                for (int r = 0; r < 4; ++r) p[r] = __builtin_amdgcn_exp2f(sf[ks][r]);
                bf16x4 pk;
#pragma unroll
                for (int r = 0; r < 4; ++r) pk[r] = (bf16)p[r];
                *(bf16x4*)&Pt[w][qs][i16 * 72 + ks * 16 + quad * 4] = pk;
                lq += (p[0] + p[1]) + (p[2] + p[3]);
            }
            lacc[qs] += lq;
        }
        asm volatile("s_waitcnt lgkmcnt(0)" ::: "memory");

        // PV: O^T[dim][query] += V_frag x P^T
#pragma unroll
        for (int qs = 0; qs < 4; ++qs) {
            const bf16x8 pb0 = *(const bf16x8*)&Pt[w][qs][i16 * 72 + 0 * 32 + quad * 8];
            const bf16x8 pb1 = *(const bf16x8*)&Pt[w][qs][i16 * 72 + 1 * 32 + quad * 8];
            o[0][qs] = MFMA(vv[0], pb0, o[0][qs]);
            o[0][qs] = MFMA(vv[1], pb1, o[0][qs]);
            o[1][qs] = MFMA(vv[2], pb0, o[1][qs]);
            o[1][qs] = MFMA(vv[3], pb1, o[1][qs]);
        }
    }

    // ---- in-block merge: stash into own Pt region (float view), 1 barrier ----
    {
        float* myo = (float*)&Pt[w][0][0]; // 9216 B region per wave
#pragma unroll
        for (int qs = 0; qs < 4; ++qs) {
            *(f32x4*)&myo[(qs * 64 + lane) * 8 + 0] = o[0][qs];
            *(f32x4*)&myo[(qs * 64 + lane) * 8 + 4] = o[1][qs];
        }
        *(f32x4*)&myo[2048 + lane * 4] = f32x4{lacc[0], lacc[1], lacc[2], lacc[3]};
    }
    __syncthreads();
    {   // wave w merges qs=w across the 4 waves, then atomics to global
        f32x4 a0 = {0.f, 0.f, 0.f, 0.f}, a1 = {0.f, 0.f, 0.f, 0.f};
        float lw = 0.f;
#pragma unroll
        for (int ww = 0; ww < 4; ++ww) {
            const float* p = (const float*)&Pt[ww][0][0];
            a0 += *(const f32x4*)&p[(w * 64 + lane) * 8 + 0];
            a1 += *(const f32x4*)&p[(w * 64 + lane) * 8 + 4];
            lw += p[2048 + lane * 4 + w];
        }
        lw += __shfl_xor(lw, 16, 64);
        lw += __shfl_xor(lw, 32, 64);
        float* dst = aof + (size_t)(q0 + w * 16 + i16) * 256 + h * 32;
#pragma unroll
        for (int r = 0; r < 4; ++r) {
            atomicAdd(&dst[quad * 4 + r], a0[r]);
            atomicAdd(&dst[16 + quad * 4 + r], a1[r]);
        }
        if (quad == 0) atomicAdd(&lvec[h * NN + q0 + w * 16 + i16], lw);
    }
}

// ---------------------------------------------------------------------------
// Output GEMM with fused softmax-normalization: A = aof (fp32, un-normalized
// attention output) scaled per (row, head=kc) by 1/lvec, hi/lo split inline.
// B = Wout^T hi/lo staged in LDS (gemm3s pattern, NTILE=16).
// ---------------------------------------------------------------------------
__global__ __launch_bounds__(256, 2) void gemm3f_kernel(const float* __restrict__ aof,
                                                        const float* __restrict__ lvec,
                                                        const bf16* __restrict__ BhT,
                                                        const bf16* __restrict__ BlT,
                                                        const float* __restrict__ bias,
                                                        float* __restrict__ C) {
    const int t = threadIdx.x, wave = t >> 6, lane = t & 63;
    const int quad = lane >> 4, i16 = lane & 15;
    const int m0 = blockIdx.x * 128 + wave * 32;
    const int n0 = blockIdx.y * 16;

    __shared__ __align__(16) bf16 Bs[16 * 512];
    {
        const int l = t & 63, i16l = l & 15, ql = l >> 4;
#pragma unroll
        for (int c = t >> 6; c < 16; c += 4) {
            const bool lo = c >= 8;
            const int kc = lo ? c - 8 : c;
            const bf16* src = (lo ? BlT : BhT) +
                (size_t)(n0 + i16l) * 256 + kc * 32 + ql * 8;
            *(uint4*)&Bs[c * 512 + l * 8] = *(const uint4*)src;
        }
    }

    bf16x8 ah[2][8], al[2][8];
#pragma unroll
    for (int ms = 0; ms < 2; ++ms) {
        const int row = m0 + ms * 16 + i16;
#pragma unroll
        for (int kc = 0; kc < 8; ++kc) {
            const float linv = 1.0f / lvec[kc * NN + row];
            const f32x4 u0 = *(const f32x4*)&aof[(size_t)row * 256 + kc * 32 + quad * 8];
            const f32x4 u1 = *(const f32x4*)&aof[(size_t)row * 256 + kc * 32 + quad * 8 + 4];
#pragma unroll
            for (int e = 0; e < 4; ++e) {
                const float v0 = u0[e] * linv, v1 = u1[e] * linv;
                const bf16 h0 = (bf16)v0, h1 = (bf16)v1;
                ah[ms][kc][e] = h0;
                ah[ms][kc][e + 4] = h1;
                al[ms][kc][e] = (bf16)(v0 - (float)h0);
                al[ms][kc][e + 4] = (bf16)(v1 - (float)h1);
            }
        }
    }
    __syncthreads();

    f32x4 acc[2];
    acc[0] = f32x4{0.f, 0.f, 0.f, 0.f};
    acc[1] = f32x4{0.f, 0.f, 0.f, 0.f};
#pragma unroll
    for (int kc = 0; kc < 8; ++kc) {
        const bf16x8 bh = *(const bf16x8*)&Bs[kc * 512 + lane * 8];
        const bf16x8 bl = *(const bf16x8*)&Bs[(8 + kc) * 512 + lane * 8];
        acc[0] = MFMA(ah[0][kc], bh, acc[0]);
        acc[0] = MFMA(ah[0][kc], bl, acc[0]);
        acc[0] = MFMA(al[0][kc], bh, acc[0]);
        acc[1] = MFMA(ah[1][kc], bh, acc[1]);
        acc[1] = MFMA(ah[1][kc], bl, acc[1]);
        acc[1] = MFMA(al[1][kc], bh, acc[1]);
    }
    const int n = n0 + i16;
    const float b = bias[n];
#pragma unroll
    for (int ms = 0; ms < 2; ++ms)
#pragma unroll
        for (int r = 0; r < 4; ++r)
            C[(size_t)(m0 + ms * 16 + quad * 4 + r) * 256 + n] = acc[ms][r] + b;
}

// ---------------------------------------------------------------------------
extern "C" void kernel_launch(void* const* d_in, const int* in_sizes, int n_in,
                              void* d_out, int out_size, void* d_ws, size_t ws_size,
                              hipStream_t stream) {
    const float* x    = (const float*)d_in[0];
    const float* pe   = (const float*)d_in[1];
    const float* Wqkv = (const float*)d_in[2];
    const float* bqkv = (const float*)d_in[3];
    const float* Wpe  = (const float*)d_in[4];
    const float* bpe  = (const float*)d_in[5];
    const float* Wout = (const float*)d_in[6];
    const float* bout = (const float*)d_in[7];
    float* out = (float*)d_out;

    char* ws = (char*)d_ws;
    bf16*  xh      = (bf16*)(ws);                   // 2 MB
    bf16*  xl      = (bf16*)(ws + 2097152);         // 2 MB
    bf16*  WqkvhT  = (bf16*)(ws + 4194304);         // 384 KB
    bf16*  WqkvlT  = (bf16*)(ws + 4587520);         // 384 KB
    bf16*  WouthT  = (bf16*)(ws + 4980736);         // 128 KB
    bf16*  WoutlT  = (bf16*)(ws + 5111808);         // 128 KB
    float* bqkv_s  = (float*)(ws + 5242880);        // 3 KB
    bf16*  qkvb    = (bf16*)(ws + 5245952);         // 6 MB
    float* ppb     = (float*)(ws + 11537408);       // 128 KB
    bf16*  Kf      = (bf16*)(ws + 11668480);        // 2 MB
    bf16*  Vf      = (bf16*)(ws + 13765632);        // 2 MB
    float* aof     = (float*)(ws + 15862784);       // 4 MB fp32 partial O
    float* lvec    = (float*)(ws + 20057088);       // 128 KB fp32 l
    uint4* zbase   = (uint4*)(ws + 15862784);       // zero region = aof+lvec

    preproc_kernel<<<2273, 256, 0, stream>>>(x, Wqkv, Wout, bqkv, pe, Wpe, bpe,
                                             xh, xl, WqkvhT, WqkvlT, WouthT, WoutlT,
                                             bqkv_s, ppb, zbase);
    gemm3s_kernel<768, 48, bf16><<<dim3(32, 16), 256, 0, stream>>>(xh, xl, WqkvhT, WqkvlT, bqkv_s, qkvb);
    kvtrans_kernel<<<dim3(HH, 64), 256, 0, stream>>>(qkvb, Kf, Vf);
    attn_kernel<<<dim3(HH, NN / 64, 2), 256, 0, stream>>>(qkvb, Kf, Vf, ppb, aof, lvec);
    gemm3f_kernel<<<dim3(32, 16), 256, 0, stream>>>(aof, lvec, WouthT, WoutlT, bout, out);
}

// Round 9
// 150.562 us; speedup vs baseline: 1.0214x; 1.0214x over previous
//
#include <hip/hip_runtime.h>
#include <math.h>

#define NN 4096
#define HH 8
constexpr float SCALE = 0.17677669529663687f;   // 1/sqrt(32)
constexpr float LOG2E = 1.4426950408889634f;
constexpr float SC2   = SCALE * LOG2E;          // folded into Q columns of Wqkv

typedef __bf16 bf16;
typedef __bf16 bf16x8 __attribute__((ext_vector_type(8)));
typedef __bf16 bf16x4 __attribute__((ext_vector_type(4)));
typedef float  f32x4  __attribute__((ext_vector_type(4)));

#define MFMA(a, b, c) __builtin_amdgcn_mfma_f32_16x16x32_bf16((a), (b), (c), 0, 0, 0)

// ---------------------------------------------------------------------------
// W [K][N] fp32 -> W^T hi/lo bf16 [N][K]; optionally scale cols n<256 by SC2.
// ---------------------------------------------------------------------------
template <int K, int N, bool SCALEQ>
__device__ __forceinline__ void wcast_body(const float* __restrict__ W,
                                           bf16* __restrict__ WhT,
                                           bf16* __restrict__ WlT,
                                           int n0, int k0, int t,
                                           float (*tile)[65]) {
#pragma unroll
    for (int p = 0; p < 16; ++p) {
        const int r = p * 4 + (t >> 6);
        const int c = t & 63;
        tile[r][c] = W[(size_t)(k0 + r) * N + n0 + c];
    }
    __syncthreads();
    const int nr = t >> 2, kc0 = (t & 3) * 16;
    const float sc = (SCALEQ && (n0 + nr) < 256) ? SC2 : 1.0f;
    bf16x8 h[2], l[2];
#pragma unroll
    for (int g = 0; g < 2; ++g)
#pragma unroll
        for (int j = 0; j < 8; ++j) {
            const float v = tile[kc0 + g * 8 + j][nr] * sc;
            const bf16 hh = (bf16)v;
            h[g][j] = hh;
            l[g][j] = (bf16)(v - (float)hh);
        }
    const size_t ob = (size_t)(n0 + nr) * K + k0 + kc0;
    *(bf16x8*)&WhT[ob] = h[0];
    *(bf16x8*)&WhT[ob + 8] = h[1];
    *(bf16x8*)&WlT[ob] = l[0];
    *(bf16x8*)&WlT[ob + 8] = l[1];
}

// ---------------------------------------------------------------------------
// Fused preprocessing (round-7 version, multiplicative ep).
// ---------------------------------------------------------------------------
__global__ __launch_bounds__(256) void preproc_kernel(
    const float* __restrict__ x, const float* __restrict__ Wqkv,
    const float* __restrict__ Wout, const float* __restrict__ bqkv,
    const float* __restrict__ pe, const float* __restrict__ Wpe,
    const float* __restrict__ bpe,
    bf16* __restrict__ xh, bf16* __restrict__ xl,
    bf16* __restrict__ WqkvhT, bf16* __restrict__ WqkvlT,
    bf16* __restrict__ WouthT, bf16* __restrict__ WoutlT,
    float* __restrict__ bqkv_s, float* __restrict__ ep) {
    __shared__ float tile[64][65];
    const int b = blockIdx.x, t = threadIdx.x;
    if (b < 1024) {
        const int i = (b * 256 + t) * 4;
        const float4 v = *(const float4*)&x[i];
        bf16x4 h, l;
        const float vv[4] = {v.x, v.y, v.z, v.w};
#pragma unroll
        for (int r = 0; r < 4; ++r) {
            h[r] = (bf16)vv[r];
            l[r] = (bf16)(vv[r] - (float)h[r]);
        }
        *(bf16x4*)&xh[i] = h;
        *(bf16x4*)&xl[i] = l;
    } else if (b < 1072) {
        const int bb = b - 1024;
        wcast_body<256, 768, true>(Wqkv, WqkvhT, WqkvlT, (bb % 12) * 64, (bb / 12) * 64, t, tile);
    } else if (b < 1088) {
        const int bb = b - 1072;
        wcast_body<256, 256, false>(Wout, WouthT, WoutlT, (bb % 4) * 64, (bb / 4) * 64, t, tile);
    } else if (b < 1216) {
        const int idx = (b - 1088) * 256 + t;
        const int h = idx >> 12;
        const int n = idx & 4095;
        float acc = bpe[h];
#pragma unroll
        for (int k = 0; k < 16; ++k) acc += pe[n * 16 + k] * Wpe[k * 8 + h];
        ep[h * NN + n] = __builtin_amdgcn_exp2f(-acc * LOG2E - 8.0f);
    } else {
        for (int i = t; i < 768; i += 256)
            bqkv_s[i] = bqkv[i] * (i < 256 ? SC2 : 1.0f);
    }
}

// ---------------------------------------------------------------------------
// Staged 3-term split-bf16 GEMM (round-6, proven).
// ---------------------------------------------------------------------------
template <int NOUT, int NTILE, typename OT>
__global__ __launch_bounds__(256, 2) void gemm3s_kernel(const bf16* __restrict__ Ah,
                                                        const bf16* __restrict__ Al,
                                                        const bf16* __restrict__ BhT,
                                                        const bf16* __restrict__ BlT,
                                                        const float* __restrict__ bias,
                                                        OT* __restrict__ C) {
    constexpr int NS = NTILE / 16;
    const int t = threadIdx.x, wave = t >> 6, lane = t & 63;
    const int quad = lane >> 4, i16 = lane & 15;
    const int m0 = blockIdx.x * 128 + wave * 32;
    const int n0 = blockIdx.y * NTILE;

    __shared__ __align__(16) bf16 Bs[NTILE * 512];

    {
        const int l = t & 63, i16l = l & 15, ql = l >> 4;
#pragma unroll
        for (int c = t >> 6; c < NS * 16; c += 4) {
            const bool lo = c >= NS * 8;
            const int cc = lo ? c - NS * 8 : c;
            const int nsi = cc >> 3, kc = cc & 7;
            const bf16* src = (lo ? BlT : BhT) +
                (size_t)(n0 + nsi * 16 + i16l) * 256 + kc * 32 + ql * 8;
            *(uint4*)&Bs[c * 512 + l * 8] = *(const uint4*)src;
        }
    }

    bf16x8 ah[2][8], al[2][8];
#pragma unroll
    for (int ms = 0; ms < 2; ++ms) {
        const size_t abase = (size_t)(m0 + ms * 16 + i16) * 256 + quad * 8;
#pragma unroll
        for (int kc = 0; kc < 8; ++kc) {
            ah[ms][kc] = *(const bf16x8*)&Ah[abase + kc * 32];
            al[ms][kc] = *(const bf16x8*)&Al[abase + kc * 32];
        }
    }
    __syncthreads();

#pragma unroll
    for (int nsi = 0; nsi < NS; ++nsi) {
        f32x4 acc[2];
        acc[0] = f32x4{0.f, 0.f, 0.f, 0.f};
        acc[1] = f32x4{0.f, 0.f, 0.f, 0.f};
#pragma unroll
        for (int kc = 0; kc < 8; ++kc) {
            const bf16x8 bh = *(const bf16x8*)&Bs[(nsi * 8 + kc) * 512 + lane * 8];
            const bf16x8 bl = *(const bf16x8*)&Bs[((NS + nsi) * 8 + kc) * 512 + lane * 8];
            acc[0] = MFMA(ah[0][kc], bh, acc[0]);
            acc[0] = MFMA(ah[0][kc], bl, acc[0]);
            acc[0] = MFMA(al[0][kc], bh, acc[0]);
            acc[1] = MFMA(ah[1][kc], bh, acc[1]);
            acc[1] = MFMA(ah[1][kc], bl, acc[1]);
            acc[1] = MFMA(al[1][kc], bh, acc[1]);
        }
        const int n = n0 + nsi * 16 + i16;
        const float b = bias[n];
#pragma unroll
        for (int ms = 0; ms < 2; ++ms)
#pragma unroll
            for (int r = 0; r < 4; ++r)
                C[(size_t)(m0 + ms * 16 + quad * 4 + r) * NOUT + n] = (OT)(acc[ms][r] + b);
    }
}

// ---------------------------------------------------------------------------
// K and V -> MFMA fragment order; V pre-scaled by ep[key] + ep-row (l trick).
// (round-7 version, proven)
// ---------------------------------------------------------------------------
__global__ __launch_bounds__(256) void kvtrans_kernel(const bf16* __restrict__ qkvb,
                                                      const float* __restrict__ ep,
                                                      bf16* __restrict__ Kf,
                                                      bf16* __restrict__ Vf) {
    const int t = threadIdx.x;
    const int kt = blockIdx.y, h = blockIdx.x;
    __shared__ __align__(16) bf16 Ktile[64 * 32];
    __shared__ __align__(16) bf16 Vtile[64 * 32];
    __shared__ float eps[64];
    {
        const int tok = kt * 64 + (t >> 2);
        const int d8 = (t & 3) * 8;
        *(uint4*)&Ktile[(t >> 2) * 32 + d8] =
            *(const uint4*)&qkvb[(size_t)tok * 768 + 256 + h * 32 + d8];
        *(uint4*)&Vtile[(t >> 2) * 32 + d8] =
            *(const uint4*)&qkvb[(size_t)tok * 768 + 512 + h * 32 + d8];
        if (t < 64) eps[t] = ep[h * NN + kt * 64 + t];
    }
    __syncthreads();
    {
        const int s = t >> 6, l = t & 63, quad = l >> 4, i16 = l & 15;
        bf16x8 o;
#pragma unroll
        for (int j = 0; j < 8; ++j) o[j] = Ktile[(s * 16 + i16) * 32 + quad * 8 + j];
        *(bf16x8*)&Kf[((size_t)(h * 64 + kt) * 4 + s) * 512 + l * 8] = o;
    }
    for (int c = t; c < 384; c += 256) {
        const int ch = c >> 6, ll = c & 63, qd = ll >> 4, ii = ll & 15;
        const int dt = ch >> 1, kc = ch & 1;
        const int dimp = dt * 16 + ii;
        bf16x8 o;
#pragma unroll
        for (int j = 0; j < 8; ++j) {
            const int key = kc * 32 + qd * 8 + j;
            float v;
            if (dimp < 32)       v = (float)Vtile[key * 32 + dimp] * eps[key];
            else if (dimp == 32) v = eps[key];
            else                 v = 0.f;
            o[j] = (bf16)v;
        }
        *(bf16x8*)&Vf[((size_t)(h * 64 + kt) * 6 + ch) * 512 + ll * 8] = o;
    }
}

// ---------------------------------------------------------------------------
// Fixed-m flash attention v5 = round-7 loop + key-half grid split + merge
// scratch aliased over Pt (LDS 36.9 KB -> 3-4 blocks/CU) + plain fp32
// partial stores (no atomics). grid (8 h, 64 qb, 2 ksh); wave w owns all 64
// queries and 8 key tiles [ksh*32 + w*8, +8).
// ---------------------------------------------------------------------------
__global__ __launch_bounds__(256, 3) void attn_kernel(const bf16* __restrict__ qkvb,
                                                      const bf16* __restrict__ Kf,
                                                      const bf16* __restrict__ Vf,
                                                      float* __restrict__ aof0,
                                                      float* __restrict__ aof1,
                                                      float* __restrict__ lv0,
                                                      float* __restrict__ lv1) {
    const int t = threadIdx.x, w = t >> 6, lane = t & 63;
    const int quad = lane >> 4, i16 = lane & 15;
    const int qb = blockIdx.y, h = blockIdx.x, ksh = blockIdx.z;

    __shared__ __align__(16) bf16 Pt[4][4][16 * 72]; // 36.9 KB; epilogue aliases

    const int q0 = qb * 64;
    bf16x8 qf[4];
#pragma unroll
    for (int qs = 0; qs < 4; ++qs)
        qf[qs] = *(const bf16x8*)&qkvb[(size_t)(q0 + qs * 16 + i16) * 768 + h * 32 + quad * 8];

    f32x4 o[3][4];
#pragma unroll
    for (int dt = 0; dt < 3; ++dt)
#pragma unroll
        for (int qs = 0; qs < 4; ++qs) o[dt][qs] = f32x4{0.f, 0.f, 0.f, 0.f};

    const bf16* kb = Kf + (size_t)(h * 64) * 2048 + lane * 8;
    const bf16* vb = Vf + (size_t)(h * 64) * 3072 + lane * 8;

    const int kt0 = ksh * 32 + w * 8;
    bf16x8 kcur[4];
#pragma unroll
    for (int s = 0; s < 4; ++s)
        kcur[s] = *(const bf16x8*)&kb[((size_t)kt0 * 4 + s) * 512];

    for (int it = 0; it < 8; ++it) {
        const int kt = kt0 + it;
        bf16x8 vv[6];
#pragma unroll
        for (int c = 0; c < 6; ++c)
            vv[c] = *(const bf16x8*)&vb[((size_t)kt * 6 + c) * 512];
        bf16x8 knx[4];
        if (it < 7) {
#pragma unroll
            for (int s = 0; s < 4; ++s)
                knx[s] = *(const bf16x8*)&kb[((size_t)(kt + 1) * 4 + s) * 512];
        } else {
#pragma unroll
            for (int s = 0; s < 4; ++s) knx[s] = kcur[s];
        }

        const f32x4 z = {0.f, 0.f, 0.f, 0.f};
#pragma unroll
        for (int qh = 0; qh < 2; ++qh) {
            f32x4 sf[2][4];
#pragma unroll
            for (int ks = 0; ks < 4; ++ks) {
                sf[0][ks] = MFMA(kcur[ks], qf[qh * 2 + 0], z);
                sf[1][ks] = MFMA(kcur[ks], qf[qh * 2 + 1], z);
            }
#pragma unroll
            for (int qi = 0; qi < 2; ++qi) {
                const int qs = qh * 2 + qi;
#pragma unroll
                for (int ks = 0; ks < 4; ++ks) {
                    bf16x4 pk;
#pragma unroll
                    for (int r = 0; r < 4; ++r)
                        pk[r] = (bf16)__builtin_amdgcn_exp2f(sf[qi][ks][r]);
                    *(bf16x4*)&Pt[w][qs][i16 * 72 + ks * 16 + quad * 4] = pk;
                }
            }
        }
        asm volatile("s_waitcnt lgkmcnt(0)" ::: "memory");

#pragma unroll
        for (int qs = 0; qs < 4; ++qs) {
            const bf16x8 pb0 = *(const bf16x8*)&Pt[w][qs][i16 * 72 + 0 * 32 + quad * 8];
            const bf16x8 pb1 = *(const bf16x8*)&Pt[w][qs][i16 * 72 + 1 * 32 + quad * 8];
#pragma unroll
            for (int dt = 0; dt < 3; ++dt) {
                o[dt][qs] = MFMA(vv[dt * 2 + 0], pb0, o[dt][qs]);
                o[dt][qs] = MFMA(vv[dt * 2 + 1], pb1, o[dt][qs]);
            }
        }
#pragma unroll
        for (int s = 0; s < 4; ++s) kcur[s] = knx[s];
    }

    // ---- epilogue: stash into own Pt region (float view), merge, store ----
    {
        float* myo = (float*)&Pt[w][0][0]; // 9216 B per-wave region (2304 fl)
#pragma unroll
        for (int qs = 0; qs < 4; ++qs) {
            *(f32x4*)&myo[(qs * 64 + lane) * 8 + 0] = o[0][qs];
            *(f32x4*)&myo[(qs * 64 + lane) * 8 + 4] = o[1][qs];
        }
        if (quad == 0) {
#pragma unroll
            for (int qs = 0; qs < 4; ++qs)
                myo[2048 + qs * 16 + i16] = o[2][qs][0]; // l (ep-row, reg0, quad0)
        }
    }
    __syncthreads();
    {   // wave w merges query-group qs=w across the 4 waves
        f32x4 a0 = {0.f, 0.f, 0.f, 0.f}, a1 = {0.f, 0.f, 0.f, 0.f};
        float lsum = 0.f;
#pragma unroll
        for (int ww = 0; ww < 4; ++ww) {
            const float* p = (const float*)&Pt[ww][0][0];
            a0 += *(const f32x4*)&p[(w * 64 + lane) * 8 + 0];
            a1 += *(const f32x4*)&p[(w * 64 + lane) * 8 + 4];
            if (lane < 16) lsum += p[2048 + w * 16 + lane];
        }
        float* aof = ksh ? aof1 : aof0;
        float* dst = aof + (size_t)(q0 + w * 16 + i16) * 256 + h * 32;
        *(f32x4*)&dst[quad * 4] = a0;
        *(f32x4*)&dst[16 + quad * 4] = a1;
        if (lane < 16) (ksh ? lv1 : lv0)[h * NN + q0 + w * 16 + lane] = lsum;
    }
}

// ---------------------------------------------------------------------------
// Output GEMM with fused key-half merge + softmax-normalization + hi/lo
// split: A = (aof0+aof1) * 1/(lv0+lv1) per (row, head=kc). B = Wout^T staged
// in LDS (gemm3s pattern, NTILE=16).
// ---------------------------------------------------------------------------
__global__ __launch_bounds__(256, 2) void gemm3f_kernel(const float* __restrict__ aof0,
                                                        const float* __restrict__ aof1,
                                                        const float* __restrict__ lv0,
                                                        const float* __restrict__ lv1,
                                                        const bf16* __restrict__ BhT,
                                                        const bf16* __restrict__ BlT,
                                                        const float* __restrict__ bias,
                                                        float* __restrict__ C) {
    const int t = threadIdx.x, wave = t >> 6, lane = t & 63;
    const int quad = lane >> 4, i16 = lane & 15;
    const int m0 = blockIdx.x * 128 + wave * 32;
    const int n0 = blockIdx.y * 16;

    __shared__ __align__(16) bf16 Bs[16 * 512];
    {
        const int l = t & 63, i16l = l & 15, ql = l >> 4;
#pragma unroll
        for (int c = t >> 6; c < 16; c += 4) {
            const bool lo = c >= 8;
            const int kc = lo ? c - 8 : c;
            const bf16* src = (lo ? BlT : BhT) +
                (size_t)(n0 + i16l) * 256 + kc * 32 + ql * 8;
            *(uint4*)&Bs[c * 512 + l * 8] = *(const uint4*)src;
        }
    }

    bf16x8 ah[2][8], al[2][8];
#pragma unroll
    for (int ms = 0; ms < 2; ++ms) {
        const int row = m0 + ms * 16 + i16;
#pragma unroll
        for (int kc = 0; kc < 8; ++kc) {
            const float linv = 1.0f / (lv0[kc * NN + row] + lv1[kc * NN + row]);
            const size_t ab = (size_t)row * 256 + kc * 32 + quad * 8;
            const f32x4 u0 = *(const f32x4*)&aof0[ab] + *(const f32x4*)&aof1[ab];
            const f32x4 u1 = *(const f32x4*)&aof0[ab + 4] + *(const f32x4*)&aof1[ab + 4];
#pragma unroll
            for (int e = 0; e < 4; ++e) {
                const float v0 = u0[e] * linv, v1 = u1[e] * linv;
                const bf16 h0 = (bf16)v0, h1 = (bf16)v1;
                ah[ms][kc][e] = h0;
                ah[ms][kc][e + 4] = h1;
                al[ms][kc][e] = (bf16)(v0 - (float)h0);
                al[ms][kc][e + 4] = (bf16)(v1 - (float)h1);
            }
        }
    }
    __syncthreads();

    f32x4 acc[2];
    acc[0] = f32x4{0.f, 0.f, 0.f, 0.f};
    acc[1] = f32x4{0.f, 0.f, 0.f, 0.f};
#pragma unroll
    for (int kc = 0; kc < 8; ++kc) {
        const bf16x8 bh = *(const bf16x8*)&Bs[kc * 512 + lane * 8];
        const bf16x8 bl = *(const bf16x8*)&Bs[(8 + kc) * 512 + lane * 8];
        acc[0] = MFMA(ah[0][kc], bh, acc[0]);
        acc[0] = MFMA(ah[0][kc], bl, acc[0]);
        acc[0] = MFMA(al[0][kc], bh, acc[0]);
        acc[1] = MFMA(ah[1][kc], bh, acc[1]);
        acc[1] = MFMA(ah[1][kc], bl, acc[1]);
        acc[1] = MFMA(al[1][kc], bh, acc[1]);
    }
    const int n = n0 + i16;
    const float b = bias[n];
#pragma unroll
    for (int ms = 0; ms < 2; ++ms)
#pragma unroll
        for (int r = 0; r < 4; ++r)
            C[(size_t)(m0 + ms * 16 + quad * 4 + r) * 256 + n] = acc[ms][r] + b;
}

// ---------------------------------------------------------------------------
extern "C" void kernel_launch(void* const* d_in, const int* in_sizes, int n_in,
                              void* d_out, int out_size, void* d_ws, size_t ws_size,
                              hipStream_t stream) {
    const float* x    = (const float*)d_in[0];
    const float* pe   = (const float*)d_in[1];
    const float* Wqkv = (const float*)d_in[2];
    const float* bqkv = (const float*)d_in[3];
    const float* Wpe  = (const float*)d_in[4];
    const float* bpe  = (const float*)d_in[5];
    const float* Wout = (const float*)d_in[6];
    const float* bout = (const float*)d_in[7];
    float* out = (float*)d_out;

    char* ws = (char*)d_ws;
    bf16*  xh      = (bf16*)(ws);                   // 2 MB
    bf16*  xl      = (bf16*)(ws + 2097152);         // 2 MB
    bf16*  WqkvhT  = (bf16*)(ws + 4194304);         // 384 KB
    bf16*  WqkvlT  = (bf16*)(ws + 4587520);         // 384 KB
    bf16*  WouthT  = (bf16*)(ws + 4980736);         // 128 KB
    bf16*  WoutlT  = (bf16*)(ws + 5111808);         // 128 KB
    float* bqkv_s  = (float*)(ws + 5242880);        // 3 KB
    bf16*  qkvb    = (bf16*)(ws + 5245952);         // 6 MB
    float* ep      = (float*)(ws + 11537408);       // 128 KB
    bf16*  Kf      = (bf16*)(ws + 11668480);        // 2 MB
    bf16*  Vf      = (bf16*)(ws + 13765632);        // 3 MB
    float* aof0    = (float*)(ws + 16911360);       // 4 MB
    float* aof1    = (float*)(ws + 21105664);       // 4 MB
    float* lv0     = (float*)(ws + 25299968);       // 128 KB
    float* lv1     = (float*)(ws + 25431040);       // 128 KB -> 25.6 MB total

    preproc_kernel<<<1217, 256, 0, stream>>>(x, Wqkv, Wout, bqkv, pe, Wpe, bpe,
                                             xh, xl, WqkvhT, WqkvlT, WouthT, WoutlT,
                                             bqkv_s, ep);
    gemm3s_kernel<768, 48, bf16><<<dim3(32, 16), 256, 0, stream>>>(xh, xl, WqkvhT, WqkvlT, bqkv_s, qkvb);
    kvtrans_kernel<<<dim3(HH, 64), 256, 0, stream>>>(qkvb, ep, Kf, Vf);
    attn_kernel<<<dim3(HH, NN / 64, 2), 256, 0, stream>>>(qkvb, Kf, Vf, aof0, aof1, lv0, lv1);
    gemm3f_kernel<<<dim3(32, 16), 256, 0, stream>>>(aof0, aof1, lv0, lv1, WouthT, WoutlT, bout, out);
}

// Round 10
// 129.870 us; speedup vs baseline: 1.1842x; 1.1593x over previous
//
#include <hip/hip_runtime.h>
#include <math.h>

#define NN 4096
#define HH 8
constexpr float SCALE = 0.17677669529663687f;   // 1/sqrt(32)
constexpr float LOG2E = 1.4426950408889634f;
constexpr float SC2   = SCALE * LOG2E;          // folded into Q columns of Wqkv

typedef __bf16 bf16;
typedef __bf16 bf16x8 __attribute__((ext_vector_type(8)));
typedef __bf16 bf16x4 __attribute__((ext_vector_type(4)));
typedef float  f32x4  __attribute__((ext_vector_type(4)));

#define MFMA(a, b, c) __builtin_amdgcn_mfma_f32_16x16x32_bf16((a), (b), (c), 0, 0, 0)

// ---------------------------------------------------------------------------
// W [K][N] fp32 -> W^T hi/lo bf16 [N][K]; optionally scale cols n<256 by SC2.
// ---------------------------------------------------------------------------
template <int K, int N, bool SCALEQ>
__device__ __forceinline__ void wcast_body(const float* __restrict__ W,
                                           bf16* __restrict__ WhT,
                                           bf16* __restrict__ WlT,
                                           int n0, int k0, int t,
                                           float (*tile)[65]) {
#pragma unroll
    for (int p = 0; p < 16; ++p) {
        const int r = p * 4 + (t >> 6);
        const int c = t & 63;
        tile[r][c] = W[(size_t)(k0 + r) * N + n0 + c];
    }
    __syncthreads();
    const int nr = t >> 2, kc0 = (t & 3) * 16;
    const float sc = (SCALEQ && (n0 + nr) < 256) ? SC2 : 1.0f;
    bf16x8 h[2], l[2];
#pragma unroll
    for (int g = 0; g < 2; ++g)
#pragma unroll
        for (int j = 0; j < 8; ++j) {
            const float v = tile[kc0 + g * 8 + j][nr] * sc;
            const bf16 hh = (bf16)v;
            h[g][j] = hh;
            l[g][j] = (bf16)(v - (float)hh);
        }
    const size_t ob = (size_t)(n0 + nr) * K + k0 + kc0;
    *(bf16x8*)&WhT[ob] = h[0];
    *(bf16x8*)&WhT[ob + 8] = h[1];
    *(bf16x8*)&WlT[ob] = l[0];
    *(bf16x8*)&WlT[ob + 8] = l[1];
}

// ---------------------------------------------------------------------------
// Fused preprocessing (xcast removed — qkv GEMM reads x directly):
//  [0,48)    wcast Wqkv (12 x 4 tiles, Q cols pre-scaled by SC2)
//  [48,64)   wcast Wout (4 x 4 tiles)
//  [64,192)  pe_proj -> ep = exp2(-(pe@Wpe+bpe)*log2e - 8)
//  [192]     bqkv scale
// ---------------------------------------------------------------------------
__global__ __launch_bounds__(256) void preproc_kernel(
    const float* __restrict__ Wqkv, const float* __restrict__ Wout,
    const float* __restrict__ bqkv, const float* __restrict__ pe,
    const float* __restrict__ Wpe, const float* __restrict__ bpe,
    bf16* __restrict__ WqkvhT, bf16* __restrict__ WqkvlT,
    bf16* __restrict__ WouthT, bf16* __restrict__ WoutlT,
    float* __restrict__ bqkv_s, float* __restrict__ ep) {
    __shared__ float tile[64][65];
    const int b = blockIdx.x, t = threadIdx.x;
    if (b < 48) {
        wcast_body<256, 768, true>(Wqkv, WqkvhT, WqkvlT, (b % 12) * 64, (b / 12) * 64, t, tile);
    } else if (b < 64) {
        const int bb = b - 48;
        wcast_body<256, 256, false>(Wout, WouthT, WoutlT, (bb % 4) * 64, (bb / 4) * 64, t, tile);
    } else if (b < 192) {
        const int idx = (b - 64) * 256 + t;
        const int h = idx >> 12;
        const int n = idx & 4095;
        float acc = bpe[h];
#pragma unroll
        for (int k = 0; k < 16; ++k) acc += pe[n * 16 + k] * Wpe[k * 8 + h];
        ep[h * NN + n] = __builtin_amdgcn_exp2f(-acc * LOG2E - 8.0f);
    } else {
        for (int i = t; i < 768; i += 256)
            bqkv_s[i] = bqkv[i] * (i < 256 ? SC2 : 1.0f);
    }
}

// ---------------------------------------------------------------------------
// Staged 3-term split-bf16 GEMM, fp32 A with inline hi/lo split (A path
// identical to the proven gemm3f): C = Ah@Bh^T + Ah@Bl^T + Al@Bh^T + bias.
// B panel staged once in LDS fragment order, shared by all 4 waves.
// ---------------------------------------------------------------------------
template <int NOUT, int NTILE, typename OT>
__global__ __launch_bounds__(256, 2) void gemm3x_kernel(const float* __restrict__ A,
                                                        const bf16* __restrict__ BhT,
                                                        const bf16* __restrict__ BlT,
                                                        const float* __restrict__ bias,
                                                        OT* __restrict__ C) {
    constexpr int NS = NTILE / 16;
    const int t = threadIdx.x, wave = t >> 6, lane = t & 63;
    const int quad = lane >> 4, i16 = lane & 15;
    const int m0 = blockIdx.x * 128 + wave * 32;
    const int n0 = blockIdx.y * NTILE;

    __shared__ __align__(16) bf16 Bs[NTILE * 512];

    {
        const int l = t & 63, i16l = l & 15, ql = l >> 4;
#pragma unroll
        for (int c = t >> 6; c < NS * 16; c += 4) {
            const bool lo = c >= NS * 8;
            const int cc = lo ? c - NS * 8 : c;
            const int nsi = cc >> 3, kc = cc & 7;
            const bf16* src = (lo ? BlT : BhT) +
                (size_t)(n0 + nsi * 16 + i16l) * 256 + kc * 32 + ql * 8;
            *(uint4*)&Bs[c * 512 + l * 8] = *(const uint4*)src;
        }
    }

    bf16x8 ah[2][8], al[2][8];
#pragma unroll
    for (int ms = 0; ms < 2; ++ms) {
        const int row = m0 + ms * 16 + i16;
#pragma unroll
        for (int kc = 0; kc < 8; ++kc) {
            const size_t ab = (size_t)row * 256 + kc * 32 + quad * 8;
            const f32x4 u0 = *(const f32x4*)&A[ab];
            const f32x4 u1 = *(const f32x4*)&A[ab + 4];
#pragma unroll
            for (int e = 0; e < 4; ++e) {
                const bf16 h0 = (bf16)u0[e], h1 = (bf16)u1[e];
                ah[ms][kc][e] = h0;
                ah[ms][kc][e + 4] = h1;
                al[ms][kc][e] = (bf16)(u0[e] - (float)h0);
                al[ms][kc][e + 4] = (bf16)(u1[e] - (float)h1);
            }
        }
    }
    __syncthreads();

#pragma unroll
    for (int nsi = 0; nsi < NS; ++nsi) {
        f32x4 acc[2];
        acc[0] = f32x4{0.f, 0.f, 0.f, 0.f};
        acc[1] = f32x4{0.f, 0.f, 0.f, 0.f};
#pragma unroll
        for (int kc = 0; kc < 8; ++kc) {
            const bf16x8 bh = *(const bf16x8*)&Bs[(nsi * 8 + kc) * 512 + lane * 8];
            const bf16x8 bl = *(const bf16x8*)&Bs[((NS + nsi) * 8 + kc) * 512 + lane * 8];
            acc[0] = MFMA(ah[0][kc], bh, acc[0]);
            acc[0] = MFMA(ah[0][kc], bl, acc[0]);
            acc[0] = MFMA(al[0][kc], bh, acc[0]);
            acc[1] = MFMA(ah[1][kc], bh, acc[1]);
            acc[1] = MFMA(ah[1][kc], bl, acc[1]);
            acc[1] = MFMA(al[1][kc], bh, acc[1]);
        }
        const int n = n0 + nsi * 16 + i16;
        const float b = bias[n];
#pragma unroll
        for (int ms = 0; ms < 2; ++ms)
#pragma unroll
            for (int r = 0; r < 4; ++r)
                C[(size_t)(m0 + ms * 16 + quad * 4 + r) * NOUT + n] = (OT)(acc[ms][r] + b);
    }
}

// ---------------------------------------------------------------------------
// Staged 3-term split-bf16 GEMM, bf16 hi/lo A (round-6, proven) — out proj.
// ---------------------------------------------------------------------------
template <int NOUT, int NTILE, typename OT>
__global__ __launch_bounds__(256, 2) void gemm3s_kernel(const bf16* __restrict__ Ah,
                                                        const bf16* __restrict__ Al,
                                                        const bf16* __restrict__ BhT,
                                                        const bf16* __restrict__ BlT,
                                                        const float* __restrict__ bias,
                                                        OT* __restrict__ C) {
    constexpr int NS = NTILE / 16;
    const int t = threadIdx.x, wave = t >> 6, lane = t & 63;
    const int quad = lane >> 4, i16 = lane & 15;
    const int m0 = blockIdx.x * 128 + wave * 32;
    const int n0 = blockIdx.y * NTILE;

    __shared__ __align__(16) bf16 Bs[NTILE * 512];

    {
        const int l = t & 63, i16l = l & 15, ql = l >> 4;
#pragma unroll
        for (int c = t >> 6; c < NS * 16; c += 4) {
            const bool lo = c >= NS * 8;
            const int cc = lo ? c - NS * 8 : c;
            const int nsi = cc >> 3, kc = cc & 7;
            const bf16* src = (lo ? BlT : BhT) +
                (size_t)(n0 + nsi * 16 + i16l) * 256 + kc * 32 + ql * 8;
            *(uint4*)&Bs[c * 512 + l * 8] = *(const uint4*)src;
        }
    }

    bf16x8 ah[2][8], al[2][8];
#pragma unroll
    for (int ms = 0; ms < 2; ++ms) {
        const size_t abase = (size_t)(m0 + ms * 16 + i16) * 256 + quad * 8;
#pragma unroll
        for (int kc = 0; kc < 8; ++kc) {
            ah[ms][kc] = *(const bf16x8*)&Ah[abase + kc * 32];
            al[ms][kc] = *(const bf16x8*)&Al[abase + kc * 32];
        }
    }
    __syncthreads();

#pragma unroll
    for (int nsi = 0; nsi < NS; ++nsi) {
        f32x4 acc[2];
        acc[0] = f32x4{0.f, 0.f, 0.f, 0.f};
        acc[1] = f32x4{0.f, 0.f, 0.f, 0.f};
#pragma unroll
        for (int kc = 0; kc < 8; ++kc) {
            const bf16x8 bh = *(const bf16x8*)&Bs[(nsi * 8 + kc) * 512 + lane * 8];
            const bf16x8 bl = *(const bf16x8*)&Bs[((NS + nsi) * 8 + kc) * 512 + lane * 8];
            acc[0] = MFMA(ah[0][kc], bh, acc[0]);
            acc[0] = MFMA(ah[0][kc], bl, acc[0]);
            acc[0] = MFMA(al[0][kc], bh, acc[0]);
            acc[1] = MFMA(ah[1][kc], bh, acc[1]);
            acc[1] = MFMA(ah[1][kc], bl, acc[1]);
            acc[1] = MFMA(al[1][kc], bh, acc[1]);
        }
        const int n = n0 + nsi * 16 + i16;
        const float b = bias[n];
#pragma unroll
        for (int ms = 0; ms < 2; ++ms)
#pragma unroll
            for (int r = 0; r < 4; ++r)
                C[(size_t)(m0 + ms * 16 + quad * 4 + r) * NOUT + n] = (OT)(acc[ms][r] + b);
    }
}

// ---------------------------------------------------------------------------
// K and V -> MFMA fragment order; V pre-scaled by ep[key] + ep-row (l trick).
// (round-7 version, proven)
// ---------------------------------------------------------------------------
__global__ __launch_bounds__(256) void kvtrans_kernel(const bf16* __restrict__ qkvb,
                                                      const float* __restrict__ ep,
                                                      bf16* __restrict__ Kf,
                                                      bf16* __restrict__ Vf) {
    const int t = threadIdx.x;
    const int kt = blockIdx.y, h = blockIdx.x;
    __shared__ __align__(16) bf16 Ktile[64 * 32];
    __shared__ __align__(16) bf16 Vtile[64 * 32];
    __shared__ float eps[64];
    {
        const int tok = kt * 64 + (t >> 2);
        const int d8 = (t & 3) * 8;
        *(uint4*)&Ktile[(t >> 2) * 32 + d8] =
            *(const uint4*)&qkvb[(size_t)tok * 768 + 256 + h * 32 + d8];
        *(uint4*)&Vtile[(t >> 2) * 32 + d8] =
            *(const uint4*)&qkvb[(size_t)tok * 768 + 512 + h * 32 + d8];
        if (t < 64) eps[t] = ep[h * NN + kt * 64 + t];
    }
    __syncthreads();
    {
        const int s = t >> 6, l = t & 63, quad = l >> 4, i16 = l & 15;
        bf16x8 o;
#pragma unroll
        for (int j = 0; j < 8; ++j) o[j] = Ktile[(s * 16 + i16) * 32 + quad * 8 + j];
        *(bf16x8*)&Kf[((size_t)(h * 64 + kt) * 4 + s) * 512 + l * 8] = o;
    }
    for (int c = t; c < 384; c += 256) {
        const int ch = c >> 6, ll = c & 63, qd = ll >> 4, ii = ll & 15;
        const int dt = ch >> 1, kc = ch & 1;
        const int dimp = dt * 16 + ii;
        bf16x8 o;
#pragma unroll
        for (int j = 0; j < 8; ++j) {
            const int key = kc * 32 + qd * 8 + j;
            float v;
            if (dimp < 32)       v = (float)Vtile[key * 32 + dimp] * eps[key];
            else if (dimp == 32) v = eps[key];
            else                 v = 0.f;
            o[j] = (bf16)v;
        }
        *(bf16x8*)&Vf[((size_t)(h * 64 + kt) * 6 + ch) * 512 + ll * 8] = o;
    }
}

// ---------------------------------------------------------------------------
// Fixed-m flash attention v6: 512-thread (8-wave) blocks, grid (8,64) = 512
// blocks -> 2 blocks/CU x 8 waves = 16 waves/CU (2x round-7 TLP). Wave w
// owns all 64 queries and key-eighth [w*8, w*8+8). No global partials: one
// barrier, in-block 8-way merge (scratch aliased over Pt). No K prefetch —
// TLP hides latency; V loaded after exp2 phase to bound register liveness.
// ---------------------------------------------------------------------------
__global__ __launch_bounds__(512, 4) void attn_kernel(const bf16* __restrict__ qkvb,
                                                      const bf16* __restrict__ Kf,
                                                      const bf16* __restrict__ Vf,
                                                      bf16* __restrict__ aoh,
                                                      bf16* __restrict__ aol) {
    const int t = threadIdx.x, w = t >> 6, lane = t & 63;
    const int quad = lane >> 4, i16 = lane & 15;
    const int qb = blockIdx.y, h = blockIdx.x;

    __shared__ __align__(16) bf16 Pt[8][4][16 * 72]; // 73.7 KB; epilogue aliases

    const int q0 = qb * 64;
    bf16x8 qf[4];
#pragma unroll
    for (int qs = 0; qs < 4; ++qs)
        qf[qs] = *(const bf16x8*)&qkvb[(size_t)(q0 + qs * 16 + i16) * 768 + h * 32 + quad * 8];

    f32x4 o[3][4];
#pragma unroll
    for (int dt = 0; dt < 3; ++dt)
#pragma unroll
        for (int qs = 0; qs < 4; ++qs) o[dt][qs] = f32x4{0.f, 0.f, 0.f, 0.f};

    const bf16* kb = Kf + (size_t)(h * 64) * 2048 + lane * 8;
    const bf16* vb = Vf + (size_t)(h * 64) * 3072 + lane * 8;

    const int kt0 = w * 8;
    for (int it = 0; it < 8; ++it) {
        const int kt = kt0 + it;
        bf16x8 kcur[4];
#pragma unroll
        for (int s = 0; s < 4; ++s)
            kcur[s] = *(const bf16x8*)&kb[((size_t)kt * 4 + s) * 512];

        // QK^T + exp2 + P-store, two query-pairs to bound sf liveness
        const f32x4 z = {0.f, 0.f, 0.f, 0.f};
#pragma unroll
        for (int qh = 0; qh < 2; ++qh) {
            f32x4 sf[2][4];
#pragma unroll
            for (int ks = 0; ks < 4; ++ks) {
                sf[0][ks] = MFMA(kcur[ks], qf[qh * 2 + 0], z);
                sf[1][ks] = MFMA(kcur[ks], qf[qh * 2 + 1], z);
            }
#pragma unroll
            for (int qi = 0; qi < 2; ++qi) {
                const int qs = qh * 2 + qi;
#pragma unroll
                for (int ks = 0; ks < 4; ++ks) {
                    bf16x4 pk;
#pragma unroll
                    for (int r = 0; r < 4; ++r)
                        pk[r] = (bf16)__builtin_amdgcn_exp2f(sf[qi][ks][r]);
                    *(bf16x4*)&Pt[w][qs][i16 * 72 + ks * 16 + quad * 4] = pk;
                }
            }
        }

        // V loads (after exp2 phase: kcur/sf dead -> lower peak liveness)
        bf16x8 vv[6];
#pragma unroll
        for (int c = 0; c < 6; ++c)
            vv[c] = *(const bf16x8*)&vb[((size_t)kt * 6 + c) * 512];
        asm volatile("s_waitcnt lgkmcnt(0)" ::: "memory");

        // PV: O^T[dim'][query] += V''_frag x P^T (o[2] quad0-reg0 = l)
#pragma unroll
        for (int qs = 0; qs < 4; ++qs) {
            const bf16x8 pb0 = *(const bf16x8*)&Pt[w][qs][i16 * 72 + 0 * 32 + quad * 8];
            const bf16x8 pb1 = *(const bf16x8*)&Pt[w][qs][i16 * 72 + 1 * 32 + quad * 8];
#pragma unroll
            for (int dt = 0; dt < 3; ++dt) {
                o[dt][qs] = MFMA(vv[dt * 2 + 0], pb0, o[dt][qs]);
                o[dt][qs] = MFMA(vv[dt * 2 + 1], pb1, o[dt][qs]);
            }
        }
    }

    // ---- epilogue: stash into own Pt region (float view), 8-way merge ----
    {
        float* myo = (float*)&Pt[w][0][0]; // 9216 B per-wave region
#pragma unroll
        for (int qs = 0; qs < 4; ++qs) {
            *(f32x4*)&myo[(qs * 64 + lane) * 8 + 0] = o[0][qs];
            *(f32x4*)&myo[(qs * 64 + lane) * 8 + 4] = o[1][qs];
        }
        if (quad == 0) {
#pragma unroll
            for (int qs = 0; qs < 4; ++qs)
                myo[2048 + qs * 16 + i16] = o[2][qs][0]; // l (ep-row, quad0 reg0)
        }
    }
    __syncthreads();
    if (w < 4) {   // wave w merges query-group qs=w across the 8 waves
        f32x4 a0 = {0.f, 0.f, 0.f, 0.f}, a1 = {0.f, 0.f, 0.f, 0.f};
        float lsum = 0.f;
#pragma unroll
        for (int ww = 0; ww < 8; ++ww) {
            const float* p = (const float*)&Pt[ww][0][0];
            a0 += *(const f32x4*)&p[(w * 64 + lane) * 8 + 0];
            a1 += *(const f32x4*)&p[(w * 64 + lane) * 8 + 4];
            if (lane < 16) lsum += p[2048 + w * 16 + lane];
        }
        const float linv = 1.0f / __shfl(lsum, i16, 64);
        const int row = q0 + w * 16 + i16;
#pragma unroll
        for (int dt = 0; dt < 2; ++dt) {
            const f32x4 src = dt ? a1 : a0;
            bf16x4 hi, lo;
#pragma unroll
            for (int r = 0; r < 4; ++r) {
                const float v = src[r] * linv;
                hi[r] = (bf16)v;
                lo[r] = (bf16)(v - (float)hi[r]);
            }
            const size_t ob = (size_t)row * 256 + h * 32 + dt * 16 + quad * 4;
            *(bf16x4*)&aoh[ob] = hi;
            *(bf16x4*)&aol[ob] = lo;
        }
    }
}

// ---------------------------------------------------------------------------
extern "C" void kernel_launch(void* const* d_in, const int* in_sizes, int n_in,
                              void* d_out, int out_size, void* d_ws, size_t ws_size,
                              hipStream_t stream) {
    const float* x    = (const float*)d_in[0];
    const float* pe   = (const float*)d_in[1];
    const float* Wqkv = (const float*)d_in[2];
    const float* bqkv = (const float*)d_in[3];
    const float* Wpe  = (const float*)d_in[4];
    const float* bpe  = (const float*)d_in[5];
    const float* Wout = (const float*)d_in[6];
    const float* bout = (const float*)d_in[7];
    float* out = (float*)d_out;

    char* ws = (char*)d_ws;
    bf16*  WqkvhT  = (bf16*)(ws);                   // 384 KB
    bf16*  WqkvlT  = (bf16*)(ws + 393216);          // 384 KB
    bf16*  WouthT  = (bf16*)(ws + 786432);          // 128 KB
    bf16*  WoutlT  = (bf16*)(ws + 917504);          // 128 KB
    float* bqkv_s  = (float*)(ws + 1048576);        // 3 KB
    bf16*  qkvb    = (bf16*)(ws + 1051648);         // 6 MB
    float* ep      = (float*)(ws + 7343104);        // 128 KB
    bf16*  Kf      = (bf16*)(ws + 7474176);         // 2 MB
    bf16*  Vf      = (bf16*)(ws + 9571328);         // 3 MB
    bf16*  aoh     = (bf16*)(ws + 12717056);        // 2 MB
    bf16*  aol     = (bf16*)(ws + 14814208);        // 2 MB -> 16.9 MB total

    preproc_kernel<<<193, 256, 0, stream>>>(Wqkv, Wout, bqkv, pe, Wpe, bpe,
                                            WqkvhT, WqkvlT, WouthT, WoutlT,
                                            bqkv_s, ep);
    gemm3x_kernel<768, 48, bf16><<<dim3(32, 16), 256, 0, stream>>>(x, WqkvhT, WqkvlT, bqkv_s, qkvb);
    kvtrans_kernel<<<dim3(HH, 64), 256, 0, stream>>>(qkvb, ep, Kf, Vf);
    attn_kernel<<<dim3(HH, NN / 64), 512, 0, stream>>>(qkvb, Kf, Vf, aoh, aol);
    gemm3s_kernel<256, 16, float><<<dim3(32, 16), 256, 0, stream>>>(aoh, aol, WouthT, WoutlT, bout, out);
}

// Round 11
// 127.763 us; speedup vs baseline: 1.2037x; 1.0165x over previous
//
#include <hip/hip_runtime.h>
#include <math.h>

#define NN 4096
#define HH 8
constexpr float SCALE = 0.17677669529663687f;   // 1/sqrt(32)
constexpr float LOG2E = 1.4426950408889634f;
constexpr float SC2   = SCALE * LOG2E;          // folded into Q columns of Wqkv

typedef __bf16 bf16;
typedef __bf16 bf16x8 __attribute__((ext_vector_type(8)));
typedef __bf16 bf16x4 __attribute__((ext_vector_type(4)));
typedef float  f32x4  __attribute__((ext_vector_type(4)));

#define MFMA(a, b, c) __builtin_amdgcn_mfma_f32_16x16x32_bf16((a), (b), (c), 0, 0, 0)

// ---------------------------------------------------------------------------
// W [K][N] fp32 -> W^T hi/lo bf16 [N][K]; optionally scale cols n<256 by SC2.
// ---------------------------------------------------------------------------
template <int K, int N, bool SCALEQ>
__device__ __forceinline__ void wcast_body(const float* __restrict__ W,
                                           bf16* __restrict__ WhT,
                                           bf16* __restrict__ WlT,
                                           int n0, int k0, int t,
                                           float (*tile)[65]) {
#pragma unroll
    for (int p = 0; p < 16; ++p) {
        const int r = p * 4 + (t >> 6);
        const int c = t & 63;
        tile[r][c] = W[(size_t)(k0 + r) * N + n0 + c];
    }
    __syncthreads();
    const int nr = t >> 2, kc0 = (t & 3) * 16;
    const float sc = (SCALEQ && (n0 + nr) < 256) ? SC2 : 1.0f;
    bf16x8 h[2], l[2];
#pragma unroll
    for (int g = 0; g < 2; ++g)
#pragma unroll
        for (int j = 0; j < 8; ++j) {
            const float v = tile[kc0 + g * 8 + j][nr] * sc;
            const bf16 hh = (bf16)v;
            h[g][j] = hh;
            l[g][j] = (bf16)(v - (float)hh);
        }
    const size_t ob = (size_t)(n0 + nr) * K + k0 + kc0;
    *(bf16x8*)&WhT[ob] = h[0];
    *(bf16x8*)&WhT[ob + 8] = h[1];
    *(bf16x8*)&WlT[ob] = l[0];
    *(bf16x8*)&WlT[ob + 8] = l[1];
}

// ---------------------------------------------------------------------------
// Fused preprocessing:
//  [0,48)    wcast Wqkv (Q cols pre-scaled by SC2)
//  [48,64)   wcast Wout
//  [64,192)  pe_proj -> ep = exp2(-(pe@Wpe+bpe)*log2e - 8)
//  [192]     bqkv scale
// ---------------------------------------------------------------------------
__global__ __launch_bounds__(256) void preproc_kernel(
    const float* __restrict__ Wqkv, const float* __restrict__ Wout,
    const float* __restrict__ bqkv, const float* __restrict__ pe,
    const float* __restrict__ Wpe, const float* __restrict__ bpe,
    bf16* __restrict__ WqkvhT, bf16* __restrict__ WqkvlT,
    bf16* __restrict__ WouthT, bf16* __restrict__ WoutlT,
    float* __restrict__ bqkv_s, float* __restrict__ ep) {
    __shared__ float tile[64][65];
    const int b = blockIdx.x, t = threadIdx.x;
    if (b < 48) {
        wcast_body<256, 768, true>(Wqkv, WqkvhT, WqkvlT, (b % 12) * 64, (b / 12) * 64, t, tile);
    } else if (b < 64) {
        const int bb = b - 48;
        wcast_body<256, 256, false>(Wout, WouthT, WoutlT, (bb % 4) * 64, (bb / 4) * 64, t, tile);
    } else if (b < 192) {
        const int idx = (b - 64) * 256 + t;
        const int h = idx >> 12;
        const int n = idx & 4095;
        float acc = bpe[h];
#pragma unroll
        for (int k = 0; k < 16; ++k) acc += pe[n * 16 + k] * Wpe[k * 8 + h];
        ep[h * NN + n] = __builtin_amdgcn_exp2f(-acc * LOG2E - 8.0f);
    } else {
        for (int i = t; i < 768; i += 256)
            bqkv_s[i] = bqkv[i] * (i < 256 ? SC2 : 1.0f);
    }
}

// ---------------------------------------------------------------------------
// Fused QKV GEMM + K/V fragment production (kvtrans deleted).
// grid (32 m-tiles of 128 tokens, 24 col-tiles of 32). NTILE=32 aligns each
// col tile with one head's 32-dim slice of Q, K, or V:
//   ct<8   : Q -> Qb row-major bf16 (attn gathers frags directly)
//   8..15  : K head ct-8 -> C tile to LDS (stride-36 rows), transpose-read in
//            MFMA A-frag order, store Kf (identical layout to old kvtrans)
//   16..23 : V head ct-16 -> kvtrans gather + ep-scale + ep-row -> Vf
// 3-term split-bf16 GEMM body (proven): fp32 A inline hi/lo split, B panel
// staged once in LDS fragment order.
// ---------------------------------------------------------------------------
__global__ __launch_bounds__(256, 2) void gemmqkv_kernel(
    const float* __restrict__ A, const bf16* __restrict__ BhT,
    const bf16* __restrict__ BlT, const float* __restrict__ bias,
    const float* __restrict__ ep,
    bf16* __restrict__ Qb, bf16* __restrict__ Kf, bf16* __restrict__ Vf) {
    const int t = threadIdx.x, wave = t >> 6, lane = t & 63;
    const int quad = lane >> 4, i16 = lane & 15;
    const int mb = blockIdx.x, ct = blockIdx.y;
    const int m0 = mb * 128 + wave * 32;
    const int n0 = ct * 32;

    __shared__ __align__(16) bf16 Bs[32 * 512];   // 32 KB B panel
    __shared__ __align__(16) bf16 Ctl[128 * 36];  // 9 KB C tile, stride 36
    __shared__ float eps[128];

    {   // stage B panel in fragment order (hi chunks 0..15, lo 16..31)
        const int i16l = lane & 15, ql = lane >> 4;
#pragma unroll
        for (int c = wave; c < 32; c += 4) {
            const bool lo = c >= 16;
            const int cc = lo ? c - 16 : c;
            const int nsi = cc >> 3, kc = cc & 7;
            const bf16* src = (lo ? BlT : BhT) +
                (size_t)(n0 + nsi * 16 + i16l) * 256 + kc * 32 + ql * 8;
            *(uint4*)&Bs[c * 512 + lane * 8] = *(const uint4*)src;
        }
    }
    if (ct >= 16 && t < 128) eps[t] = ep[(ct - 16) * NN + mb * 128 + t];

    // A fragments with inline hi/lo split
    bf16x8 ah[2][8], al[2][8];
#pragma unroll
    for (int ms = 0; ms < 2; ++ms) {
        const int row = m0 + ms * 16 + i16;
#pragma unroll
        for (int kc = 0; kc < 8; ++kc) {
            const size_t ab = (size_t)row * 256 + kc * 32 + quad * 8;
            const f32x4 u0 = *(const f32x4*)&A[ab];
            const f32x4 u1 = *(const f32x4*)&A[ab + 4];
#pragma unroll
            for (int e = 0; e < 4; ++e) {
                const bf16 h0 = (bf16)u0[e], h1 = (bf16)u1[e];
                ah[ms][kc][e] = h0;
                ah[ms][kc][e + 4] = h1;
                al[ms][kc][e] = (bf16)(u0[e] - (float)h0);
                al[ms][kc][e + 4] = (bf16)(u1[e] - (float)h1);
            }
        }
    }
    __syncthreads();

    f32x4 acc[2][2]; // [nsi][ms]
#pragma unroll
    for (int nsi = 0; nsi < 2; ++nsi) {
        acc[nsi][0] = f32x4{0.f, 0.f, 0.f, 0.f};
        acc[nsi][1] = f32x4{0.f, 0.f, 0.f, 0.f};
#pragma unroll
        for (int kc = 0; kc < 8; ++kc) {
            const bf16x8 bh = *(const bf16x8*)&Bs[(nsi * 8 + kc) * 512 + lane * 8];
            const bf16x8 bl = *(const bf16x8*)&Bs[((2 + nsi) * 8 + kc) * 512 + lane * 8];
            acc[nsi][0] = MFMA(ah[0][kc], bh, acc[nsi][0]);
            acc[nsi][0] = MFMA(ah[0][kc], bl, acc[nsi][0]);
            acc[nsi][0] = MFMA(al[0][kc], bh, acc[nsi][0]);
            acc[nsi][1] = MFMA(ah[1][kc], bh, acc[nsi][1]);
            acc[nsi][1] = MFMA(ah[1][kc], bl, acc[nsi][1]);
            acc[nsi][1] = MFMA(al[1][kc], bh, acc[nsi][1]);
        }
    }

    if (ct < 8) {
        // Q: row-major bf16 store (cols pre-scaled by SC2 via W/bias prep)
#pragma unroll
        for (int nsi = 0; nsi < 2; ++nsi) {
            const int n = n0 + nsi * 16 + i16;
            const float b = bias[n];
#pragma unroll
            for (int ms = 0; ms < 2; ++ms)
#pragma unroll
                for (int r = 0; r < 4; ++r)
                    Qb[(size_t)(m0 + ms * 16 + quad * 4 + r) * 256 + n] =
                        (bf16)(acc[nsi][ms][r] + b);
        }
        return;
    }

    // K/V: bias + cast into LDS C tile (rows local 0..127, stride 36)
#pragma unroll
    for (int nsi = 0; nsi < 2; ++nsi) {
        const int n = n0 + nsi * 16 + i16;
        const float b = bias[n];
#pragma unroll
        for (int ms = 0; ms < 2; ++ms)
#pragma unroll
            for (int r = 0; r < 4; ++r)
                Ctl[(wave * 32 + ms * 16 + quad * 4 + r) * 36 + nsi * 16 + i16] =
                    (bf16)(acc[nsi][ms][r] + b);
    }
    __syncthreads();

    if (ct < 16) {
        const int h = ct - 8;
        // K frags: 8 chunks (2 key tiles x 4 key-subs), b128 transpose reads
#pragma unroll
        for (int c = wave; c < 8; c += 4) {
            const int half = c >> 2, s = c & 3;
            bf16x8 o;
#pragma unroll
            for (int j = 0; j < 8; ++j)
                o[j] = Ctl[(half * 64 + s * 16 + i16) * 36 + quad * 8 + j];
            *(bf16x8*)&Kf[((size_t)(h * 64 + mb * 2 + half) * 4 + s) * 512 + lane * 8] = o;
        }
    } else {
        const int h = ct - 16;
        // V'' frags: 12 chunks (2 key tiles x [3 d-tiles x 2 key-halves]),
        // ep-scaled, with ep-row at dim'=32 (softmax-l trick)
#pragma unroll
        for (int c = wave; c < 12; c += 4) {
            const int half = c / 6, ch = c % 6;
            const int dt = ch >> 1, kc = ch & 1;
            const int dimp = dt * 16 + i16;
            bf16x8 o;
#pragma unroll
            for (int j = 0; j < 8; ++j) {
                const int key = half * 64 + kc * 32 + quad * 8 + j; // local
                float v;
                if (dimp < 32)       v = (float)Ctl[key * 36 + dimp] * eps[key];
                else if (dimp == 32) v = eps[key];
                else                 v = 0.f;
                o[j] = (bf16)v;
            }
            *(bf16x8*)&Vf[((size_t)(h * 64 + mb * 2 + half) * 6 + ch) * 512 + lane * 8] = o;
        }
    }
}

// ---------------------------------------------------------------------------
// Staged 3-term split-bf16 GEMM, bf16 hi/lo A (round-6, proven) — out proj.
// ---------------------------------------------------------------------------
template <int NOUT, int NTILE, typename OT>
__global__ __launch_bounds__(256, 2) void gemm3s_kernel(const bf16* __restrict__ Ah,
                                                        const bf16* __restrict__ Al,
                                                        const bf16* __restrict__ BhT,
                                                        const bf16* __restrict__ BlT,
                                                        const float* __restrict__ bias,
                                                        OT* __restrict__ C) {
    constexpr int NS = NTILE / 16;
    const int t = threadIdx.x, wave = t >> 6, lane = t & 63;
    const int quad = lane >> 4, i16 = lane & 15;
    const int m0 = blockIdx.x * 128 + wave * 32;
    const int n0 = blockIdx.y * NTILE;

    __shared__ __align__(16) bf16 Bs[NTILE * 512];

    {
        const int l = t & 63, i16l = l & 15, ql = l >> 4;
#pragma unroll
        for (int c = t >> 6; c < NS * 16; c += 4) {
            const bool lo = c >= NS * 8;
            const int cc = lo ? c - NS * 8 : c;
            const int nsi = cc >> 3, kc = cc & 7;
            const bf16* src = (lo ? BlT : BhT) +
                (size_t)(n0 + nsi * 16 + i16l) * 256 + kc * 32 + ql * 8;
            *(uint4*)&Bs[c * 512 + l * 8] = *(const uint4*)src;
        }
    }

    bf16x8 ah[2][8], al[2][8];
#pragma unroll
    for (int ms = 0; ms < 2; ++ms) {
        const size_t abase = (size_t)(m0 + ms * 16 + i16) * 256 + quad * 8;
#pragma unroll
        for (int kc = 0; kc < 8; ++kc) {
            ah[ms][kc] = *(const bf16x8*)&Ah[abase + kc * 32];
            al[ms][kc] = *(const bf16x8*)&Al[abase + kc * 32];
        }
    }
    __syncthreads();

#pragma unroll
    for (int nsi = 0; nsi < NS; ++nsi) {
        f32x4 acc[2];
        acc[0] = f32x4{0.f, 0.f, 0.f, 0.f};
        acc[1] = f32x4{0.f, 0.f, 0.f, 0.f};
#pragma unroll
        for (int kc = 0; kc < 8; ++kc) {
            const bf16x8 bh = *(const bf16x8*)&Bs[(nsi * 8 + kc) * 512 + lane * 8];
            const bf16x8 bl = *(const bf16x8*)&Bs[((NS + nsi) * 8 + kc) * 512 + lane * 8];
            acc[0] = MFMA(ah[0][kc], bh, acc[0]);
            acc[0] = MFMA(ah[0][kc], bl, acc[0]);
            acc[0] = MFMA(al[0][kc], bh, acc[0]);
            acc[1] = MFMA(ah[1][kc], bh, acc[1]);
            acc[1] = MFMA(ah[1][kc], bl, acc[1]);
            acc[1] = MFMA(al[1][kc], bh, acc[1]);
        }
        const int n = n0 + nsi * 16 + i16;
        const float b = bias[n];
#pragma unroll
        for (int ms = 0; ms < 2; ++ms)
#pragma unroll
            for (int r = 0; r < 4; ++r)
                C[(size_t)(m0 + ms * 16 + quad * 4 + r) * NOUT + n] = (OT)(acc[ms][r] + b);
    }
}

// ---------------------------------------------------------------------------
// Fixed-m flash attention (round-10, proven): 512-thread (8-wave) blocks,
// grid (8,64); wave w owns all 64 queries and key-eighth [w*8, w*8+8).
// One barrier; in-block 8-way merge; l from V'' ep-row. Q from compact Qb.
// ---------------------------------------------------------------------------
__global__ __launch_bounds__(512, 4) void attn_kernel(const bf16* __restrict__ Qb,
                                                      const bf16* __restrict__ Kf,
                                                      const bf16* __restrict__ Vf,
                                                      bf16* __restrict__ aoh,
                                                      bf16* __restrict__ aol) {
    const int t = threadIdx.x, w = t >> 6, lane = t & 63;
    const int quad = lane >> 4, i16 = lane & 15;
    const int qb = blockIdx.y, h = blockIdx.x;

    __shared__ __align__(16) bf16 Pt[8][4][16 * 72]; // 73.7 KB; epilogue aliases

    const int q0 = qb * 64;
    bf16x8 qf[4];
#pragma unroll
    for (int qs = 0; qs < 4; ++qs)
        qf[qs] = *(const bf16x8*)&Qb[(size_t)(q0 + qs * 16 + i16) * 256 + h * 32 + quad * 8];

    f32x4 o[3][4];
#pragma unroll
    for (int dt = 0; dt < 3; ++dt)
#pragma unroll
        for (int qs = 0; qs < 4; ++qs) o[dt][qs] = f32x4{0.f, 0.f, 0.f, 0.f};

    const bf16* kb = Kf + (size_t)(h * 64) * 2048 + lane * 8;
    const bf16* vb = Vf + (size_t)(h * 64) * 3072 + lane * 8;

    const int kt0 = w * 8;
    for (int it = 0; it < 8; ++it) {
        const int kt = kt0 + it;
        bf16x8 kcur[4];
#pragma unroll
        for (int s = 0; s < 4; ++s)
            kcur[s] = *(const bf16x8*)&kb[((size_t)kt * 4 + s) * 512];

        const f32x4 z = {0.f, 0.f, 0.f, 0.f};
#pragma unroll
        for (int qh = 0; qh < 2; ++qh) {
            f32x4 sf[2][4];
#pragma unroll
            for (int ks = 0; ks < 4; ++ks) {
                sf[0][ks] = MFMA(kcur[ks], qf[qh * 2 + 0], z);
                sf[1][ks] = MFMA(kcur[ks], qf[qh * 2 + 1], z);
            }
#pragma unroll
            for (int qi = 0; qi < 2; ++qi) {
                const int qs = qh * 2 + qi;
#pragma unroll
                for (int ks = 0; ks < 4; ++ks) {
                    bf16x4 pk;
#pragma unroll
                    for (int r = 0; r < 4; ++r)
                        pk[r] = (bf16)__builtin_amdgcn_exp2f(sf[qi][ks][r]);
                    *(bf16x4*)&Pt[w][qs][i16 * 72 + ks * 16 + quad * 4] = pk;
                }
            }
        }

        bf16x8 vv[6];
#pragma unroll
        for (int c = 0; c < 6; ++c)
            vv[c] = *(const bf16x8*)&vb[((size_t)kt * 6 + c) * 512];
        asm volatile("s_waitcnt lgkmcnt(0)" ::: "memory");

#pragma unroll
        for (int qs = 0; qs < 4; ++qs) {
            const bf16x8 pb0 = *(const bf16x8*)&Pt[w][qs][i16 * 72 + 0 * 32 + quad * 8];
            const bf16x8 pb1 = *(const bf16x8*)&Pt[w][qs][i16 * 72 + 1 * 32 + quad * 8];
#pragma unroll
            for (int dt = 0; dt < 3; ++dt) {
                o[dt][qs] = MFMA(vv[dt * 2 + 0], pb0, o[dt][qs]);
                o[dt][qs] = MFMA(vv[dt * 2 + 1], pb1, o[dt][qs]);
            }
        }
    }

    {
        float* myo = (float*)&Pt[w][0][0];
#pragma unroll
        for (int qs = 0; qs < 4; ++qs) {
            *(f32x4*)&myo[(qs * 64 + lane) * 8 + 0] = o[0][qs];
            *(f32x4*)&myo[(qs * 64 + lane) * 8 + 4] = o[1][qs];
        }
        if (quad == 0) {
#pragma unroll
            for (int qs = 0; qs < 4; ++qs)
                myo[2048 + qs * 16 + i16] = o[2][qs][0];
        }
    }
    __syncthreads();
    if (w < 4) {
        f32x4 a0 = {0.f, 0.f, 0.f, 0.f}, a1 = {0.f, 0.f, 0.f, 0.f};
        float lsum = 0.f;
#pragma unroll
        for (int ww = 0; ww < 8; ++ww) {
            const float* p = (const float*)&Pt[ww][0][0];
            a0 += *(const f32x4*)&p[(w * 64 + lane) * 8 + 0];
            a1 += *(const f32x4*)&p[(w * 64 + lane) * 8 + 4];
            if (lane < 16) lsum += p[2048 + w * 16 + lane];
        }
        const float linv = 1.0f / __shfl(lsum, i16, 64);
        const int row = q0 + w * 16 + i16;
#pragma unroll
        for (int dt = 0; dt < 2; ++dt) {
            const f32x4 src = dt ? a1 : a0;
            bf16x4 hi, lo;
#pragma unroll
            for (int r = 0; r < 4; ++r) {
                const float v = src[r] * linv;
                hi[r] = (bf16)v;
                lo[r] = (bf16)(v - (float)hi[r]);
            }
            const size_t ob = (size_t)row * 256 + h * 32 + dt * 16 + quad * 4;
            *(bf16x4*)&aoh[ob] = hi;
            *(bf16x4*)&aol[ob] = lo;
        }
    }
}

// ---------------------------------------------------------------------------
extern "C" void kernel_launch(void* const* d_in, const int* in_sizes, int n_in,
                              void* d_out, int out_size, void* d_ws, size_t ws_size,
                              hipStream_t stream) {
    const float* x    = (const float*)d_in[0];
    const float* pe   = (const float*)d_in[1];
    const float* Wqkv = (const float*)d_in[2];
    const float* bqkv = (const float*)d_in[3];
    const float* Wpe  = (const float*)d_in[4];
    const float* bpe  = (const float*)d_in[5];
    const float* Wout = (const float*)d_in[6];
    const float* bout = (const float*)d_in[7];
    float* out = (float*)d_out;

    char* ws = (char*)d_ws;
    bf16*  WqkvhT  = (bf16*)(ws);                   // 384 KB
    bf16*  WqkvlT  = (bf16*)(ws + 393216);          // 384 KB
    bf16*  WouthT  = (bf16*)(ws + 786432);          // 128 KB
    bf16*  WoutlT  = (bf16*)(ws + 917504);          // 128 KB
    float* bqkv_s  = (float*)(ws + 1048576);        // 3 KB
    float* ep      = (float*)(ws + 1051648);        // 128 KB
    bf16*  Qb      = (bf16*)(ws + 1182720);         // 2 MB
    bf16*  Kf      = (bf16*)(ws + 3279872);         // 2 MB
    bf16*  Vf      = (bf16*)(ws + 5377024);         // 3 MB
    bf16*  aoh     = (bf16*)(ws + 8522752);         // 2 MB
    bf16*  aol     = (bf16*)(ws + 10619904);        // 2 MB -> 12.7 MB total

    preproc_kernel<<<193, 256, 0, stream>>>(Wqkv, Wout, bqkv, pe, Wpe, bpe,
                                            WqkvhT, WqkvlT, WouthT, WoutlT,
                                            bqkv_s, ep);
    gemmqkv_kernel<<<dim3(32, 24), 256, 0, stream>>>(x, WqkvhT, WqkvlT, bqkv_s, ep,
                                                     Qb, Kf, Vf);
    attn_kernel<<<dim3(HH, NN / 64), 512, 0, stream>>>(Qb, Kf, Vf, aoh, aol);
    gemm3s_kernel<256, 16, float><<<dim3(32, 16), 256, 0, stream>>>(aoh, aol, WouthT, WoutlT, bout, out);
}

// Round 12
// 126.482 us; speedup vs baseline: 1.2159x; 1.0101x over previous
//
#include <hip/hip_runtime.h>
#include <math.h>

#define NN 4096
#define HH 8
constexpr float SCALE = 0.17677669529663687f;   // 1/sqrt(32)
constexpr float LOG2E = 1.4426950408889634f;
constexpr float SC2   = SCALE * LOG2E;          // folded into Q columns of Wqkv

typedef __bf16 bf16;
typedef __bf16 bf16x8 __attribute__((ext_vector_type(8)));
typedef __bf16 bf16x4 __attribute__((ext_vector_type(4)));
typedef float  f32x4  __attribute__((ext_vector_type(4)));

#define MFMA(a, b, c) __builtin_amdgcn_mfma_f32_16x16x32_bf16((a), (b), (c), 0, 0, 0)

// ---------------------------------------------------------------------------
// W [K][N] fp32 -> W^T hi/lo bf16 [N][K]; optionally scale cols n<256 by SC2.
// ---------------------------------------------------------------------------
template <int K, int N, bool SCALEQ>
__device__ __forceinline__ void wcast_body(const float* __restrict__ W,
                                           bf16* __restrict__ WhT,
                                           bf16* __restrict__ WlT,
                                           int n0, int k0, int t,
                                           float (*tile)[65]) {
#pragma unroll
    for (int p = 0; p < 16; ++p) {
        const int r = p * 4 + (t >> 6);
        const int c = t & 63;
        tile[r][c] = W[(size_t)(k0 + r) * N + n0 + c];
    }
    __syncthreads();
    const int nr = t >> 2, kc0 = (t & 3) * 16;
    const float sc = (SCALEQ && (n0 + nr) < 256) ? SC2 : 1.0f;
    bf16x8 h[2], l[2];
#pragma unroll
    for (int g = 0; g < 2; ++g)
#pragma unroll
        for (int j = 0; j < 8; ++j) {
            const float v = tile[kc0 + g * 8 + j][nr] * sc;
            const bf16 hh = (bf16)v;
            h[g][j] = hh;
            l[g][j] = (bf16)(v - (float)hh);
        }
    const size_t ob = (size_t)(n0 + nr) * K + k0 + kc0;
    *(bf16x8*)&WhT[ob] = h[0];
    *(bf16x8*)&WhT[ob + 8] = h[1];
    *(bf16x8*)&WlT[ob] = l[0];
    *(bf16x8*)&WlT[ob + 8] = l[1];
}

// ---------------------------------------------------------------------------
// Preprocessing, minimal: ONLY the Wqkv cast (the sole true predecessor of
// gemmqkv). ep / bias-scale / Wout-cast all moved into gemmqkv's shadow.
// ---------------------------------------------------------------------------
__global__ __launch_bounds__(256) void preproc_kernel(const float* __restrict__ Wqkv,
                                                      bf16* __restrict__ WqkvhT,
                                                      bf16* __restrict__ WqkvlT) {
    __shared__ float tile[64][65];
    const int b = blockIdx.x, t = threadIdx.x;
    wcast_body<256, 768, true>(Wqkv, WqkvhT, WqkvlT, (b % 12) * 64, (b / 12) * 64, t, tile);
}

// ---------------------------------------------------------------------------
// Fused QKV GEMM + K/V fragment production + inline ep + inline bias scale
// + piggybacked Wout cast.
// grid (32 m-tiles of 128 tokens, 25):
//   ct<8   : Q -> Qb row-major bf16 (bias scaled by SC2 inline)
//   8..15  : K head ct-8 -> C tile via LDS -> Kf (MFMA A-frag order)
//   16..23 : V head ct-16 -> ep computed inline (dot16+exp2), kvtrans gather
//            + ep-scale + ep-row -> Vf
//   24     : mb<16: Wout wcast tile (rides the grid's tail slack); else exit
// ---------------------------------------------------------------------------
__global__ __launch_bounds__(256, 2) void gemmqkv_kernel(
    const float* __restrict__ A, const bf16* __restrict__ BhT,
    const bf16* __restrict__ BlT, const float* __restrict__ bqkv,
    const float* __restrict__ pe, const float* __restrict__ Wpe,
    const float* __restrict__ bpe, const float* __restrict__ Wout,
    bf16* __restrict__ Qb, bf16* __restrict__ Kf, bf16* __restrict__ Vf,
    bf16* __restrict__ WouthT, bf16* __restrict__ WoutlT) {
    const int t = threadIdx.x, wave = t >> 6, lane = t & 63;
    const int quad = lane >> 4, i16 = lane & 15;
    const int mb = blockIdx.x, ct = blockIdx.y;

    __shared__ __align__(16) bf16 Bs[32 * 512];   // 32 KB B panel
    __shared__ __align__(16) bf16 Ctl[128 * 36];  // 9 KB C tile, stride 36
    __shared__ float eps[128];

    if (ct == 24) {   // piggybacked Wout cast (16 tiles); uniform branch
        if (mb < 16)
            wcast_body<256, 256, false>(Wout, WouthT, WoutlT,
                                        (mb % 4) * 64, (mb / 4) * 64, t,
                                        (float(*)[65]) & Bs[0]);
        return;
    }

    const int m0 = mb * 128 + wave * 32;
    const int n0 = ct * 32;

    {   // stage B panel in fragment order (hi chunks 0..15, lo 16..31)
        const int i16l = lane & 15, ql = lane >> 4;
#pragma unroll
        for (int c = wave; c < 32; c += 4) {
            const bool lo = c >= 16;
            const int cc = lo ? c - 16 : c;
            const int nsi = cc >> 3, kc = cc & 7;
            const bf16* src = (lo ? BlT : BhT) +
                (size_t)(n0 + nsi * 16 + i16l) * 256 + kc * 32 + ql * 8;
            *(uint4*)&Bs[c * 512 + lane * 8] = *(const uint4*)src;
        }
    }
    if (ct >= 16 && t < 128) {   // inline pe-projection for this head/token-tile
        const int h = ct - 16, n = mb * 128 + t;
        float acc = bpe[h];
#pragma unroll
        for (int k = 0; k < 16; ++k) acc += pe[n * 16 + k] * Wpe[k * 8 + h];
        eps[t] = __builtin_amdgcn_exp2f(-acc * LOG2E - 8.0f);
    }

    // A fragments with inline hi/lo split
    bf16x8 ah[2][8], al[2][8];
#pragma unroll
    for (int ms = 0; ms < 2; ++ms) {
        const int row = m0 + ms * 16 + i16;
#pragma unroll
        for (int kc = 0; kc < 8; ++kc) {
            const size_t ab = (size_t)row * 256 + kc * 32 + quad * 8;
            const f32x4 u0 = *(const f32x4*)&A[ab];
            const f32x4 u1 = *(const f32x4*)&A[ab + 4];
#pragma unroll
            for (int e = 0; e < 4; ++e) {
                const bf16 h0 = (bf16)u0[e], h1 = (bf16)u1[e];
                ah[ms][kc][e] = h0;
                ah[ms][kc][e + 4] = h1;
                al[ms][kc][e] = (bf16)(u0[e] - (float)h0);
                al[ms][kc][e + 4] = (bf16)(u1[e] - (float)h1);
            }
        }
    }
    __syncthreads();

    f32x4 acc[2][2]; // [nsi][ms]
#pragma unroll
    for (int nsi = 0; nsi < 2; ++nsi) {
        acc[nsi][0] = f32x4{0.f, 0.f, 0.f, 0.f};
        acc[nsi][1] = f32x4{0.f, 0.f, 0.f, 0.f};
#pragma unroll
        for (int kc = 0; kc < 8; ++kc) {
            const bf16x8 bh = *(const bf16x8*)&Bs[(nsi * 8 + kc) * 512 + lane * 8];
            const bf16x8 bl = *(const bf16x8*)&Bs[((2 + nsi) * 8 + kc) * 512 + lane * 8];
            acc[nsi][0] = MFMA(ah[0][kc], bh, acc[nsi][0]);
            acc[nsi][0] = MFMA(ah[0][kc], bl, acc[nsi][0]);
            acc[nsi][0] = MFMA(al[0][kc], bh, acc[nsi][0]);
            acc[nsi][1] = MFMA(ah[1][kc], bh, acc[nsi][1]);
            acc[nsi][1] = MFMA(ah[1][kc], bl, acc[nsi][1]);
            acc[nsi][1] = MFMA(al[1][kc], bh, acc[nsi][1]);
        }
    }

    if (ct < 8) {
        // Q: row-major bf16 store, bias scaled by SC2 inline (n < 256 always)
#pragma unroll
        for (int nsi = 0; nsi < 2; ++nsi) {
            const int n = n0 + nsi * 16 + i16;
            const float b = bqkv[n] * SC2;
#pragma unroll
            for (int ms = 0; ms < 2; ++ms)
#pragma unroll
                for (int r = 0; r < 4; ++r)
                    Qb[(size_t)(m0 + ms * 16 + quad * 4 + r) * 256 + n] =
                        (bf16)(acc[nsi][ms][r] + b);
        }
        return;
    }

    // K/V: bias + cast into LDS C tile (rows local 0..127, stride 36)
#pragma unroll
    for (int nsi = 0; nsi < 2; ++nsi) {
        const int n = n0 + nsi * 16 + i16;
        const float b = bqkv[n];
#pragma unroll
        for (int ms = 0; ms < 2; ++ms)
#pragma unroll
            for (int r = 0; r < 4; ++r)
                Ctl[(wave * 32 + ms * 16 + quad * 4 + r) * 36 + nsi * 16 + i16] =
                    (bf16)(acc[nsi][ms][r] + b);
    }
    __syncthreads();

    if (ct < 16) {
        const int h = ct - 8;
        // K frags: 8 chunks (2 key tiles x 4 key-subs), b128 transpose reads
#pragma unroll
        for (int c = wave; c < 8; c += 4) {
            const int half = c >> 2, s = c & 3;
            bf16x8 o;
#pragma unroll
            for (int j = 0; j < 8; ++j)
                o[j] = Ctl[(half * 64 + s * 16 + i16) * 36 + quad * 8 + j];
            *(bf16x8*)&Kf[((size_t)(h * 64 + mb * 2 + half) * 4 + s) * 512 + lane * 8] = o;
        }
    } else {
        const int h = ct - 16;
        // V'' frags: 12 chunks (2 key tiles x [3 d-tiles x 2 key-halves]),
        // ep-scaled, with ep-row at dim'=32 (softmax-l trick)
#pragma unroll
        for (int c = wave; c < 12; c += 4) {
            const int half = c / 6, ch = c % 6;
            const int dt = ch >> 1, kc = ch & 1;
            const int dimp = dt * 16 + i16;
            bf16x8 o;
#pragma unroll
            for (int j = 0; j < 8; ++j) {
                const int key = half * 64 + kc * 32 + quad * 8 + j; // local
                float v;
                if (dimp < 32)       v = (float)Ctl[key * 36 + dimp] * eps[key];
                else if (dimp == 32) v = eps[key];
                else                 v = 0.f;
                o[j] = (bf16)v;
            }
            *(bf16x8*)&Vf[((size_t)(h * 64 + mb * 2 + half) * 6 + ch) * 512 + lane * 8] = o;
        }
    }
}

// ---------------------------------------------------------------------------
// Staged 3-term split-bf16 GEMM, bf16 hi/lo A (round-6, proven) — out proj.
// ---------------------------------------------------------------------------
template <int NOUT, int NTILE, typename OT>
__global__ __launch_bounds__(256, 2) void gemm3s_kernel(const bf16* __restrict__ Ah,
                                                        const bf16* __restrict__ Al,
                                                        const bf16* __restrict__ BhT,
                                                        const bf16* __restrict__ BlT,
                                                        const float* __restrict__ bias,
                                                        OT* __restrict__ C) {
    constexpr int NS = NTILE / 16;
    const int t = threadIdx.x, wave = t >> 6, lane = t & 63;
    const int quad = lane >> 4, i16 = lane & 15;
    const int m0 = blockIdx.x * 128 + wave * 32;
    const int n0 = blockIdx.y * NTILE;

    __shared__ __align__(16) bf16 Bs[NTILE * 512];

    {
        const int l = t & 63, i16l = l & 15, ql = l >> 4;
#pragma unroll
        for (int c = t >> 6; c < NS * 16; c += 4) {
            const bool lo = c >= NS * 8;
            const int cc = lo ? c - NS * 8 : c;
            const int nsi = cc >> 3, kc = cc & 7;
            const bf16* src = (lo ? BlT : BhT) +
                (size_t)(n0 + nsi * 16 + i16l) * 256 + kc * 32 + ql * 8;
            *(uint4*)&Bs[c * 512 + l * 8] = *(const uint4*)src;
        }
    }

    bf16x8 ah[2][8], al[2][8];
#pragma unroll
    for (int ms = 0; ms < 2; ++ms) {
        const size_t abase = (size_t)(m0 + ms * 16 + i16) * 256 + quad * 8;
#pragma unroll
        for (int kc = 0; kc < 8; ++kc) {
            ah[ms][kc] = *(const bf16x8*)&Ah[abase + kc * 32];
            al[ms][kc] = *(const bf16x8*)&Al[abase + kc * 32];
        }
    }
    __syncthreads();

#pragma unroll
    for (int nsi = 0; nsi < NS; ++nsi) {
        f32x4 acc[2];
        acc[0] = f32x4{0.f, 0.f, 0.f, 0.f};
        acc[1] = f32x4{0.f, 0.f, 0.f, 0.f};
#pragma unroll
        for (int kc = 0; kc < 8; ++kc) {
            const bf16x8 bh = *(const bf16x8*)&Bs[(nsi * 8 + kc) * 512 + lane * 8];
            const bf16x8 bl = *(const bf16x8*)&Bs[((NS + nsi) * 8 + kc) * 512 + lane * 8];
            acc[0] = MFMA(ah[0][kc], bh, acc[0]);
            acc[0] = MFMA(ah[0][kc], bl, acc[0]);
            acc[0] = MFMA(al[0][kc], bh, acc[0]);
            acc[1] = MFMA(ah[1][kc], bh, acc[1]);
            acc[1] = MFMA(ah[1][kc], bl, acc[1]);
            acc[1] = MFMA(al[1][kc], bh, acc[1]);
        }
        const int n = n0 + nsi * 16 + i16;
        const float b = bias[n];
#pragma unroll
        for (int ms = 0; ms < 2; ++ms)
#pragma unroll
            for (int r = 0; r < 4; ++r)
                C[(size_t)(m0 + ms * 16 + quad * 4 + r) * NOUT + n] = (OT)(acc[ms][r] + b);
    }
}

// ---------------------------------------------------------------------------
// Fixed-m flash attention (round-10/11, proven): 512-thread (8-wave) blocks,
// grid (8,64); wave w owns all 64 queries and key-eighth [w*8, w*8+8).
// One barrier; in-block 8-way merge; l from V'' ep-row. Q from compact Qb.
// ---------------------------------------------------------------------------
__global__ __launch_bounds__(512, 4) void attn_kernel(const bf16* __restrict__ Qb,
                                                      const bf16* __restrict__ Kf,
                                                      const bf16* __restrict__ Vf,
                                                      bf16* __restrict__ aoh,
                                                      bf16* __restrict__ aol) {
    const int t = threadIdx.x, w = t >> 6, lane = t & 63;
    const int quad = lane >> 4, i16 = lane & 15;
    const int qb = blockIdx.y, h = blockIdx.x;

    __shared__ __align__(16) bf16 Pt[8][4][16 * 72]; // 73.7 KB; epilogue aliases

    const int q0 = qb * 64;
    bf16x8 qf[4];
#pragma unroll
    for (int qs = 0; qs < 4; ++qs)
        qf[qs] = *(const bf16x8*)&Qb[(size_t)(q0 + qs * 16 + i16) * 256 + h * 32 + quad * 8];

    f32x4 o[3][4];
#pragma unroll
    for (int dt = 0; dt < 3; ++dt)
#pragma unroll
        for (int qs = 0; qs < 4; ++qs) o[dt][qs] = f32x4{0.f, 0.f, 0.f, 0.f};

    const bf16* kb = Kf + (size_t)(h * 64) * 2048 + lane * 8;
    const bf16* vb = Vf + (size_t)(h * 64) * 3072 + lane * 8;

    const int kt0 = w * 8;
    for (int it = 0; it < 8; ++it) {
        const int kt = kt0 + it;
        bf16x8 kcur[4];
#pragma unroll
        for (int s = 0; s < 4; ++s)
            kcur[s] = *(const bf16x8*)&kb[((size_t)kt * 4 + s) * 512];

        const f32x4 z = {0.f, 0.f, 0.f, 0.f};
#pragma unroll
        for (int qh = 0; qh < 2; ++qh) {
            f32x4 sf[2][4];
#pragma unroll
            for (int ks = 0; ks < 4; ++ks) {
                sf[0][ks] = MFMA(kcur[ks], qf[qh * 2 + 0], z);
                sf[1][ks] = MFMA(kcur[ks], qf[qh * 2 + 1], z);
            }
#pragma unroll
            for (int qi = 0; qi < 2; ++qi) {
                const int qs = qh * 2 + qi;
#pragma unroll
                for (int ks = 0; ks < 4; ++ks) {
                    bf16x4 pk;
#pragma unroll
                    for (int r = 0; r < 4; ++r)
                        pk[r] = (bf16)__builtin_amdgcn_exp2f(sf[qi][ks][r]);
                    *(bf16x4*)&Pt[w][qs][i16 * 72 + ks * 16 + quad * 4] = pk;
                }
            }
        }

        bf16x8 vv[6];
#pragma unroll
        for (int c = 0; c < 6; ++c)
            vv[c] = *(const bf16x8*)&vb[((size_t)kt * 6 + c) * 512];
        asm volatile("s_waitcnt lgkmcnt(0)" ::: "memory");

#pragma unroll
        for (int qs = 0; qs < 4; ++qs) {
            const bf16x8 pb0 = *(const bf16x8*)&Pt[w][qs][i16 * 72 + 0 * 32 + quad * 8];
            const bf16x8 pb1 = *(const bf16x8*)&Pt[w][qs][i16 * 72 + 1 * 32 + quad * 8];
#pragma unroll
            for (int dt = 0; dt < 3; ++dt) {
                o[dt][qs] = MFMA(vv[dt * 2 + 0], pb0, o[dt][qs]);
                o[dt][qs] = MFMA(vv[dt * 2 + 1], pb1, o[dt][qs]);
            }
        }
    }

    {
        float* myo = (float*)&Pt[w][0][0];
#pragma unroll
        for (int qs = 0; qs < 4; ++qs) {
            *(f32x4*)&myo[(qs * 64 + lane) * 8 + 0] = o[0][qs];
            *(f32x4*)&myo[(qs * 64 + lane) * 8 + 4] = o[1][qs];
        }
        if (quad == 0) {
#pragma unroll
            for (int qs = 0; qs < 4; ++qs)
                myo[2048 + qs * 16 + i16] = o[2][qs][0];
        }
    }
    __syncthreads();
    if (w < 4) {
        f32x4 a0 = {0.f, 0.f, 0.f, 0.f}, a1 = {0.f, 0.f, 0.f, 0.f};
        float lsum = 0.f;
#pragma unroll
        for (int ww = 0; ww < 8; ++ww) {
            const float* p = (const float*)&Pt[ww][0][0];
            a0 += *(const f32x4*)&p[(w * 64 + lane) * 8 + 0];
            a1 += *(const f32x4*)&p[(w * 64 + lane) * 8 + 4];
            if (lane < 16) lsum += p[2048 + w * 16 + lane];
        }
        const float linv = 1.0f / __shfl(lsum, i16, 64);
        const int row = q0 + w * 16 + i16;
#pragma unroll
        for (int dt = 0; dt < 2; ++dt) {
            const f32x4 src = dt ? a1 : a0;
            bf16x4 hi, lo;
#pragma unroll
            for (int r = 0; r < 4; ++r) {
                const float v = src[r] * linv;
                hi[r] = (bf16)v;
                lo[r] = (bf16)(v - (float)hi[r]);
            }
            const size_t ob = (size_t)row * 256 + h * 32 + dt * 16 + quad * 4;
            *(bf16x4*)&aoh[ob] = hi;
            *(bf16x4*)&aol[ob] = lo;
        }
    }
}

// ---------------------------------------------------------------------------
extern "C" void kernel_launch(void* const* d_in, const int* in_sizes, int n_in,
                              void* d_out, int out_size, void* d_ws, size_t ws_size,
                              hipStream_t stream) {
    const float* x    = (const float*)d_in[0];
    const float* pe   = (const float*)d_in[1];
    const float* Wqkv = (const float*)d_in[2];
    const float* bqkv = (const float*)d_in[3];
    const float* Wpe  = (const float*)d_in[4];
    const float* bpe  = (const float*)d_in[5];
    const float* Wout = (const float*)d_in[6];
    const float* bout = (const float*)d_in[7];
    float* out = (float*)d_out;

    char* ws = (char*)d_ws;
    bf16*  WqkvhT  = (bf16*)(ws);                   // 384 KB
    bf16*  WqkvlT  = (bf16*)(ws + 393216);          // 384 KB
    bf16*  WouthT  = (bf16*)(ws + 786432);          // 128 KB
    bf16*  WoutlT  = (bf16*)(ws + 917504);          // 128 KB
    bf16*  Qb      = (bf16*)(ws + 1048576);         // 2 MB
    bf16*  Kf      = (bf16*)(ws + 3145728);         // 2 MB
    bf16*  Vf      = (bf16*)(ws + 5242880);         // 3 MB
    bf16*  aoh     = (bf16*)(ws + 8388608);         // 2 MB
    bf16*  aol     = (bf16*)(ws + 10485760);        // 2 MB -> 12.6 MB total

    preproc_kernel<<<48, 256, 0, stream>>>(Wqkv, WqkvhT, WqkvlT);
    gemmqkv_kernel<<<dim3(32, 25), 256, 0, stream>>>(x, WqkvhT, WqkvlT, bqkv,
                                                     pe, Wpe, bpe, Wout,
                                                     Qb, Kf, Vf, WouthT, WoutlT);
    attn_kernel<<<dim3(HH, NN / 64), 512, 0, stream>>>(Qb, Kf, Vf, aoh, aol);
    gemm3s_kernel<256, 16, float><<<dim3(32, 16), 256, 0, stream>>>(aoh, aol, WouthT, WoutlT, bout, out);
}